// Round 1
// baseline (609.968 us; speedup 1.0000x reference)
//
#include <hip/hip_runtime.h>
#include <hip/hip_bf16.h>

using u16 = unsigned short;
using u32 = unsigned int;
typedef short short8 __attribute__((ext_vector_type(8)));
typedef float f32x4 __attribute__((ext_vector_type(4)));

#define B_  2
#define S_  2048
#define E_  768
#define BS_ 4096

__device__ __forceinline__ u16 f2bf(float f) {
  __hip_bfloat16 h = __float2bfloat16(f);
  return *reinterpret_cast<u16*>(&h);
}

// async global->LDS, 16B per lane. LDS dest must be wave-uniform base + lane*16.
__device__ __forceinline__ void gld16(const void* g, void* l) {
  __builtin_amdgcn_global_load_lds(
      (const __attribute__((address_space(1))) u32*)g,
      (__attribute__((address_space(3))) u32*)l, 16, 0, 0);
}

// ---------------- conversion / misc kernels ----------------

__global__ __launch_bounds__(256) void conv_x_k(const float* __restrict__ x,
                                                u16* __restrict__ xb, int n4) {
  int i = blockIdx.x * 256 + threadIdx.x;
  if (i >= n4) return;
  float4 v = reinterpret_cast<const float4*>(x)[i];
  u32 lo = (u32)f2bf(v.x) | ((u32)f2bf(v.y) << 16);
  u32 hi = (u32)f2bf(v.z) | ((u32)f2bf(v.w) << 16);
  reinterpret_cast<uint2*>(xb)[i] = make_uint2(lo, hi);
}

__global__ __launch_bounds__(256) void bias_k(
    const float* rqb, const float* rkb, const float* rvb,
    const float* cqb, const float* ckb, const float* cvb,
    const float* rob, const float* cob,
    const float* rcb, const float* ccb,
    float* bqkv, float* bproj) {
  int t = blockIdx.x * 256 + threadIdx.x;
  if (t < 4608) {
    int seg = t / 768, i = t - seg * 768;
    float v = 0.f;
    if      (seg == 0) v = rqb[i] + rcb[i];   // cultural bias folds into Q bias
    else if (seg == 1) v = rkb[i];
    else if (seg == 2) v = rvb[i];
    else if (seg == 3) v = cqb[i] + ccb[i];
    else if (seg == 4) v = ckb[i];
    else               v = cvb[i];
    bqkv[t] = v;
  } else {
    int u = t - 4608;
    if (u < 1536) bproj[u] = (u < 768) ? rob[u] : cob[u - 768];
  }
}

struct TP {
  const float* src[9];
  u16* dst[9];
  int rows[9];
};

// dst[c][r] = bf16(src[r][c]); src is [rows][768]
__global__ __launch_bounds__(256) void transpose_k(TP p) {
  int mi = blockIdx.z;
  int rows = p.rows[mi];
  int r0 = blockIdx.y * 32;
  if (r0 >= rows) return;
  int c0 = blockIdx.x * 32;
  const float* src = p.src[mi];
  u16* dst = p.dst[mi];
  __shared__ float t[32][33];
  int tx = threadIdx.x & 31, ty = threadIdx.x >> 5;
#pragma unroll
  for (int d = 0; d < 4; ++d) {
    int r = ty + d * 8;
    t[r][tx] = src[(size_t)(r0 + r) * 768 + c0 + tx];
  }
  __syncthreads();
#pragma unroll
  for (int d = 0; d < 4; ++d) {
    int c = ty + d * 8;
    dst[(size_t)(c0 + c) * rows + r0 + tx] = f2bf(t[tx][c]);
  }
}

// ---------------- generic GEMM: C[M,N] = A[M,K] * BT[N,K]^T + bias ----------------
// MODE 0: write bf16 to Cout (with optional n-split selecting second B / A col offset)
// MODE 1: write fp32 to Cout
// MODE 2: QKV epilogue routing (Q/K per-head layout, V transposed)

template<int MODE>
__global__ __launch_bounds__(256) void gemm_k(
    const u16* __restrict__ A, int lda,
    const u16* __restrict__ BT, int ldb,
    const float* __restrict__ bias, int K,
    const u16* __restrict__ BT2, int nsplit, int acol2,
    void* __restrict__ Cout, int ldc,
    u16* __restrict__ Qr, u16* __restrict__ Kr, u16* __restrict__ Vtr,
    u16* __restrict__ Qc, u16* __restrict__ Kc, u16* __restrict__ Vtc) {
  __shared__ u16 lA[128 * 32];
  __shared__ u16 lB[128 * 32];
  const int tid = threadIdx.x, w = tid >> 6, lane = tid & 63;
  const int quad = lane >> 4, l15 = lane & 15;
  const int m0 = blockIdx.y * 128, n0 = blockIdx.x * 128;
  if (nsplit && n0 >= nsplit) { A += acol2; BT = BT2 - (size_t)nsplit * ldb; }

  const f32x4 z4 = {0.f, 0.f, 0.f, 0.f};
  f32x4 acc[4][4];
#pragma unroll
  for (int i = 0; i < 4; ++i)
#pragma unroll
    for (int j = 0; j < 4; ++j) acc[i][j] = z4;

  const int sr = w * 32 + (lane >> 2);  // staging row (this call); +16 for second
  const int scp = lane & 3;             // staging chunk position within 64B row

  for (int kt = 0; kt < K; kt += 32) {
    int r1 = sr, r2 = sr + 16;
    int c1 = (scp - (r1 >> 2)) & 3;  // swizzled source chunk (2-way-free reads)
    int c2 = (scp - (r2 >> 2)) & 3;
    gld16(A + (size_t)(m0 + r1) * lda + kt + c1 * 8, &lA[r1 * 32 + scp * 8]);
    gld16(A + (size_t)(m0 + r2) * lda + kt + c2 * 8, &lA[r2 * 32 + scp * 8]);
    gld16(BT + (size_t)(n0 + r1) * ldb + kt + c1 * 8, &lB[r1 * 32 + scp * 8]);
    gld16(BT + (size_t)(n0 + r2) * ldb + kt + c2 * 8, &lB[r2 * 32 + scp * 8]);
    __syncthreads();
    short8 af[4], bg[4];
#pragma unroll
    for (int i = 0; i < 4; ++i) {
      int r = (w >> 1) * 64 + i * 16 + l15;
      af[i] = *reinterpret_cast<const short8*>(&lA[r * 32 + ((quad + (r >> 2)) & 3) * 8]);
    }
#pragma unroll
    for (int j = 0; j < 4; ++j) {
      int r = (w & 1) * 64 + j * 16 + l15;
      bg[j] = *reinterpret_cast<const short8*>(&lB[r * 32 + ((quad + (r >> 2)) & 3) * 8]);
    }
#pragma unroll
    for (int i = 0; i < 4; ++i)
#pragma unroll
      for (int j = 0; j < 4; ++j)
        acc[i][j] = __builtin_amdgcn_mfma_f32_16x16x32_bf16(af[i], bg[j], acc[i][j], 0, 0, 0);
    __syncthreads();
  }

#pragma unroll
  for (int i = 0; i < 4; ++i) {
#pragma unroll
    for (int j = 0; j < 4; ++j) {
#pragma unroll
      for (int r = 0; r < 4; ++r) {
        int row = m0 + (w >> 1) * 64 + i * 16 + quad * 4 + r;
        int col = n0 + (w & 1) * 64 + j * 16 + l15;
        float v = acc[i][j][r] + bias[col];
        if (MODE == 0) {
          reinterpret_cast<u16*>(Cout)[(size_t)row * ldc + col] = f2bf(v);
        } else if (MODE == 1) {
          reinterpret_cast<float*>(Cout)[(size_t)row * ldc + col] = v;
        } else {
          int seg = col / 768, cs = col - seg * 768;
          int b = row >> 11, s = row & 2047;
          u16 hv = f2bf(v);
          if (seg == 0) { int h = cs >> 7, d = cs & 127; Qr[((size_t)(b * 6 + h) * 2048 + s) * 128 + d] = hv; }
          else if (seg == 1) { int h = cs >> 7, d = cs & 127; Kr[((size_t)(b * 6 + h) * 2048 + s) * 128 + d] = hv; }
          else if (seg == 2) { int h = cs >> 7, d = cs & 127; Vtr[((size_t)(b * 6 + h) * 128 + d) * 2048 + s] = hv; }
          else if (seg == 3) { int h = cs / 384, d = cs - h * 384; Qc[((size_t)(b * 2 + h) * 2048 + s) * 384 + d] = hv; }
          else if (seg == 4) { int h = cs / 384, d = cs - h * 384; Kc[((size_t)(b * 2 + h) * 2048 + s) * 384 + d] = hv; }
          else               { int h = cs / 384, d = cs - h * 384; Vtc[((size_t)(b * 2 + h) * 384 + d) * 2048 + s] = hv; }
        }
      }
    }
  }
}

// ---------------- flash attention ----------------
// Block: 256 threads (4 waves), 64 q-rows (16 per wave), 32-key tiles.
// Q: [bh][S][HD] bf16 (bias+cb folded). K: [bh][S][HD]. Vt: [bh][HD][S].
template<int HD, int CUL>
__global__ __launch_bounds__(256) void attn_k(
    const u16* __restrict__ Qp, const u16* __restrict__ Kp, const u16* __restrict__ Vtp,
    const float* __restrict__ am, const float* __restrict__ cmask,
    u16* __restrict__ AO, int nh, int col_off, float scale) {
  constexpr int CPR = HD / 8;  // 16B chunks per lK row
  __shared__ u16 lK[32 * HD];
  __shared__ u16 lV[HD * 32];
  __shared__ u16 lP[4 * 16 * 32];
  __shared__ float lC[CUL ? 64 * 32 : 32];

  const int tid = threadIdx.x, w = tid >> 6, lane = tid & 63;
  const int quad = lane >> 4, l15 = lane & 15;
  const int q0 = blockIdx.x * 64;
  const int bh = blockIdx.y;
  const int b = bh / nh;
  const int h = bh - b * nh;
  const u16* Qb = Qp + ((size_t)bh * S_ + q0) * HD;
  const u16* Kb = Kp + (size_t)bh * S_ * HD;
  const u16* Vb = Vtp + (size_t)bh * HD * S_;
  const float* amb = am + b * S_;
  const float* cmb = CUL ? (cmask + (size_t)b * S_ * S_ + (size_t)q0 * S_) : nullptr;

  // preload Q fragments (A-operand layout)
  short8 qf[HD / 32];
  {
    const u16* qrow = Qb + (size_t)(w * 16 + l15) * HD + quad * 8;
#pragma unroll
    for (int c = 0; c < HD / 32; ++c)
      qf[c] = *reinterpret_cast<const short8*>(qrow + c * 32);
  }
  const f32x4 z4 = {0.f, 0.f, 0.f, 0.f};
  f32x4 O[HD / 16];
#pragma unroll
  for (int j = 0; j < HD / 16; ++j) O[j] = z4;
  float mrow[4], lrow[4];
#pragma unroll
  for (int r = 0; r < 4; ++r) { mrow[r] = -INFINITY; lrow[r] = 0.f; }

  for (int k0 = 0; k0 < S_; k0 += 32) {
    // stage K tile [32][HD], swizzled within 16-chunk groups
#pragma unroll
    for (int it = 0; it < (4 * HD) / 256; ++it) {
      int idx = it * 256 + tid;
      int n = idx / CPR, cp = idx - n * CPR;
      int c = (cp & ~15) | ((cp - n) & 15);
      gld16(Kb + (size_t)(k0 + n) * HD + c * 8, &lK[idx * 8]);
    }
    // stage Vt tile [HD][32], additive swizzle by n>>2
#pragma unroll
    for (int it = 0; it < (4 * HD) / 256; ++it) {
      int idx = it * 256 + tid;
      int n = idx >> 2, cp = idx & 3;
      int c = (cp - (n >> 2)) & 3;
      gld16(Vb + (size_t)n * S_ + k0 + c * 8, &lV[idx * 8]);
    }
    if (CUL) {
#pragma unroll
      for (int it = 0; it < 2; ++it) {
        int idx = it * 256 + tid;
        int r = idx >> 3, cg = idx & 7;
        gld16(cmb + (size_t)r * S_ + k0 + cg * 4, &lC[idx * 4]);
      }
    }
    __syncthreads();

    // S = Q K^T (16 q-rows x 32 keys per wave)
    f32x4 s0 = z4, s1 = z4;
#pragma unroll
    for (int c = 0; c < HD / 32; ++c) {
      int rcp = c * 4 + quad;
      int nA = l15, nB = 16 + l15;
      int swA = (rcp & ~15) | ((rcp + nA) & 15);
      int swB = (rcp & ~15) | ((rcp + nB) & 15);
      short8 b0 = *reinterpret_cast<const short8*>(&lK[(nA * CPR + swA) * 8]);
      short8 b1 = *reinterpret_cast<const short8*>(&lK[(nB * CPR + swB) * 8]);
      s0 = __builtin_amdgcn_mfma_f32_16x16x32_bf16(qf[c], b0, s0, 0, 0, 0);
      s1 = __builtin_amdgcn_mfma_f32_16x16x32_bf16(qf[c], b1, s1, 0, 0, 0);
    }
    float amv0 = amb[k0 + l15];
    float amv1 = amb[k0 + 16 + l15];

    // online softmax + P -> LDS (bf16)
#pragma unroll
    for (int r = 0; r < 4; ++r) {
      int mm = quad * 4 + r;
      float v0 = s0[r] * scale + amv0;
      float v1 = s1[r] * scale + amv1;
      if (CUL) {
        int lrq = w * 16 + mm;
        v0 += lC[lrq * 32 + l15];
        v1 += lC[lrq * 32 + 16 + l15];
      }
      float mx = fmaxf(v0, v1);
      mx = fmaxf(mx, __shfl_xor(mx, 1));
      mx = fmaxf(mx, __shfl_xor(mx, 2));
      mx = fmaxf(mx, __shfl_xor(mx, 4));
      mx = fmaxf(mx, __shfl_xor(mx, 8));
      float mnew = fmaxf(mrow[r], mx);
      float alpha = __expf(mrow[r] - mnew);
      mrow[r] = mnew;
      float p0 = __expf(v0 - mnew);
      float p1 = __expf(v1 - mnew);
      float rs = p0 + p1;
      rs += __shfl_xor(rs, 1);
      rs += __shfl_xor(rs, 2);
      rs += __shfl_xor(rs, 4);
      rs += __shfl_xor(rs, 8);
      lrow[r] = lrow[r] * alpha + rs;
#pragma unroll
      for (int j = 0; j < HD / 16; ++j) O[j][r] *= alpha;
      int wb = w * 512;
      int cA = l15 >> 3, cB = 2 + cA;
      lP[wb + mm * 32 + ((cA + (mm >> 2)) & 3) * 8 + (l15 & 7)] = f2bf(p0);
      lP[wb + mm * 32 + ((cB + (mm >> 2)) & 3) * 8 + (l15 & 7)] = f2bf(p1);
    }

    // O += P V  (P a-frag from per-wave LDS; Vt gives B^T layout)
    short8 pa;
    {
      int m = l15;
      pa = *reinterpret_cast<const short8*>(&lP[w * 512 + m * 32 + ((quad + (m >> 2)) & 3) * 8]);
    }
#pragma unroll
    for (int j = 0; j < HD / 16; ++j) {
      int n = j * 16 + l15;
      short8 bv = *reinterpret_cast<const short8*>(&lV[n * 32 + ((quad + (n >> 2)) & 3) * 8]);
      O[j] = __builtin_amdgcn_mfma_f32_16x16x32_bf16(pa, bv, O[j], 0, 0, 0);
    }
    __syncthreads();
  }

  // epilogue: O / l -> AO (bf16), feature = h*HD + d
#pragma unroll
  for (int j = 0; j < HD / 16; ++j) {
#pragma unroll
    for (int r = 0; r < 4; ++r) {
      int row = q0 + w * 16 + quad * 4 + r;
      int col = col_off + h * HD + j * 16 + l15;
      AO[((size_t)(b * S_ + row)) * 1536 + col] = f2bf(O[j][r] / lrow[r]);
    }
  }
}

// ---------------- launcher ----------------

extern "C" void kernel_launch(void* const* d_in, const int* in_sizes, int n_in,
                              void* d_out, int out_size, void* d_ws, size_t ws_size,
                              hipStream_t stream) {
  const float* x     = (const float*)d_in[0];
  const float* cmask = (const float*)d_in[1];
  const float* amask = (const float*)d_in[2];
  const float* W[8]  = { (const float*)d_in[3], (const float*)d_in[4], (const float*)d_in[5],
                         (const float*)d_in[6], (const float*)d_in[7], (const float*)d_in[8],
                         (const float*)d_in[9], (const float*)d_in[10] };
  const float* rq_b = (const float*)d_in[11];
  const float* rk_b = (const float*)d_in[12];
  const float* rv_b = (const float*)d_in[13];
  const float* ro_b = (const float*)d_in[14];
  const float* cq_b = (const float*)d_in[15];
  const float* ck_b = (const float*)d_in[16];
  const float* cv_b = (const float*)d_in[17];
  const float* co_b = (const float*)d_in[18];
  const float* r_cb = (const float*)d_in[19];
  const float* c_cb = (const float*)d_in[20];
  const float* out_w = (const float*)d_in[21];
  const float* out_b = (const float*)d_in[22];

  char* p = (char*)d_ws;
  auto carve = [&](size_t bytes) -> void* {
    void* r = (void*)p;
    p += (bytes + 255) & ~(size_t)255;
    return r;
  };
  u16* Xb    = (u16*)carve((size_t)BS_ * E_ * 2);
  u16* WqkvT = (u16*)carve((size_t)4608 * 768 * 2);
  u16* roT   = (u16*)carve((size_t)768 * 768 * 2);
  u16* coT   = (u16*)carve((size_t)768 * 768 * 2);
  u16* outwT = (u16*)carve((size_t)768 * 1536 * 2);
  float* bqkv  = (float*)carve(4608 * 4);
  float* bproj = (float*)carve(1536 * 4);
  u16* Qr  = (u16*)carve((size_t)B_ * 6 * S_ * 128 * 2);
  u16* Kr  = (u16*)carve((size_t)B_ * 6 * S_ * 128 * 2);
  u16* Vtr = (u16*)carve((size_t)B_ * 6 * S_ * 128 * 2);
  u16* Qc  = (u16*)carve((size_t)B_ * 2 * S_ * 384 * 2);
  u16* Kc  = (u16*)carve((size_t)B_ * 2 * S_ * 384 * 2);
  u16* Vtc = (u16*)carve((size_t)B_ * 2 * S_ * 384 * 2);
  u16* AO  = (u16*)carve((size_t)BS_ * 1536 * 2);
  u16* PR  = (u16*)carve((size_t)BS_ * 1536 * 2);

  conv_x_k<<<dim3(BS_ * E_ / 4 / 256), 256, 0, stream>>>(x, Xb, BS_ * E_ / 4);
  bias_k<<<dim3(24), 256, 0, stream>>>(rq_b, rk_b, rv_b, cq_b, ck_b, cv_b,
                                       ro_b, co_b, r_cb, c_cb, bqkv, bproj);

  TP tp;
  const int wsel[6] = {0, 1, 2, 4, 5, 6};  // rq rk rv cq ck cv
  for (int i = 0; i < 6; ++i) {
    tp.src[i] = W[wsel[i]];
    tp.dst[i] = WqkvT + (size_t)i * 768 * 768;
    tp.rows[i] = 768;
  }
  tp.src[6] = W[3]; tp.dst[6] = roT;   tp.rows[6] = 768;   // ro_w
  tp.src[7] = W[7]; tp.dst[7] = coT;   tp.rows[7] = 768;   // co_w
  tp.src[8] = out_w; tp.dst[8] = outwT; tp.rows[8] = 1536; // out_w
  transpose_k<<<dim3(24, 48, 9), 256, 0, stream>>>(tp);

  // fused QKV projection for both branches (N = 6*768)
  gemm_k<2><<<dim3(36, 32), 256, 0, stream>>>(
      Xb, 768, WqkvT, 768, bqkv, 768,
      (const u16*)nullptr, 0, 0, (void*)nullptr, 0,
      Qr, Kr, Vtr, Qc, Kc, Vtc);

  attn_k<128, 0><<<dim3(32, 12), 256, 0, stream>>>(
      Qr, Kr, Vtr, amask, (const float*)nullptr, AO, 6, 0, 0.08838834764831845f);
  attn_k<384, 1><<<dim3(32, 4), 256, 0, stream>>>(
      Qc, Kc, Vtc, amask, cmask, AO, 2, 768, 0.05103103630798288f);

  // merged per-branch output projections (block-diagonal select on n)
  gemm_k<0><<<dim3(12, 32), 256, 0, stream>>>(
      AO, 1536, roT, 768, bproj, 768,
      coT, 768, 768, (void*)PR, 1536,
      nullptr, nullptr, nullptr, nullptr, nullptr, nullptr);

  // final: PR[4096,1536] @ out_w + out_b -> fp32 d_out
  gemm_k<1><<<dim3(6, 32), 256, 0, stream>>>(
      PR, 1536, outwT, 1536, out_b, 1536,
      (const u16*)nullptr, 0, 0, d_out, 768,
      nullptr, nullptr, nullptr, nullptr, nullptr, nullptr);
}

// Round 2
// 484.140 us; speedup vs baseline: 1.2599x; 1.2599x over previous
//
#include <hip/hip_runtime.h>
#include <hip/hip_bf16.h>

using u16 = unsigned short;
using u32 = unsigned int;
typedef short short8 __attribute__((ext_vector_type(8)));
typedef float f32x4 __attribute__((ext_vector_type(4)));

#define B_  2
#define S_  2048
#define E_  768
#define BS_ 4096

__device__ __forceinline__ u16 f2bf(float f) {
  __hip_bfloat16 h = __float2bfloat16(f);
  return *reinterpret_cast<u16*>(&h);
}

__device__ __forceinline__ float bf2f(u16 b) {
  u32 bits = (u32)b << 16;
  return *reinterpret_cast<float*>(&bits);
}

// async global->LDS, 16B per lane. LDS dest must be wave-uniform base + lane*16.
__device__ __forceinline__ void gld16(const void* g, void* l) {
  __builtin_amdgcn_global_load_lds(
      (const __attribute__((address_space(1))) u32*)g,
      (__attribute__((address_space(3))) u32*)l, 16, 0, 0);
}

// ---------------- conversion / misc kernels ----------------

__global__ __launch_bounds__(256) void conv_x_k(const float* __restrict__ x,
                                                u16* __restrict__ xb, int n4) {
  int i = blockIdx.x * 256 + threadIdx.x;
  if (i >= n4) return;
  float4 v = reinterpret_cast<const float4*>(x)[i];
  u32 lo = (u32)f2bf(v.x) | ((u32)f2bf(v.y) << 16);
  u32 hi = (u32)f2bf(v.z) | ((u32)f2bf(v.w) << 16);
  reinterpret_cast<uint2*>(xb)[i] = make_uint2(lo, hi);
}

__global__ __launch_bounds__(256) void bias_k(
    const float* rqb, const float* rkb, const float* rvb,
    const float* cqb, const float* ckb, const float* cvb,
    const float* rob, const float* cob,
    const float* rcb, const float* ccb,
    float* bqkv, float* bproj) {
  int t = blockIdx.x * 256 + threadIdx.x;
  if (t < 4608) {
    int seg = t / 768, i = t - seg * 768;
    float v = 0.f;
    if      (seg == 0) v = rqb[i] + rcb[i];   // cultural bias folds into Q bias
    else if (seg == 1) v = rkb[i];
    else if (seg == 2) v = rvb[i];
    else if (seg == 3) v = cqb[i] + ccb[i];
    else if (seg == 4) v = ckb[i];
    else               v = cvb[i];
    bqkv[t] = v;
  } else {
    int u = t - 4608;
    if (u < 1536) bproj[u] = (u < 768) ? rob[u] : cob[u - 768];
  }
}

struct TP {
  const float* src[9];
  u16* dst[9];
  int rows[9];
};

// dst[c][r] = bf16(src[r][c]); src is [rows][768]
__global__ __launch_bounds__(256) void transpose_k(TP p) {
  int mi = blockIdx.z;
  int rows = p.rows[mi];
  int r0 = blockIdx.y * 32;
  if (r0 >= rows) return;
  int c0 = blockIdx.x * 32;
  const float* src = p.src[mi];
  u16* dst = p.dst[mi];
  __shared__ float t[32][33];
  int tx = threadIdx.x & 31, ty = threadIdx.x >> 5;
#pragma unroll
  for (int d = 0; d < 4; ++d) {
    int r = ty + d * 8;
    t[r][tx] = src[(size_t)(r0 + r) * 768 + c0 + tx];
  }
  __syncthreads();
#pragma unroll
  for (int d = 0; d < 4; ++d) {
    int c = ty + d * 8;
    dst[(size_t)(c0 + c) * rows + r0 + tx] = f2bf(t[tx][c]);
  }
}

// ---------------- generic GEMM: C[M,N] = A[M,K] * BT[N,K]^T + bias ----------------
// MODE 0: write bf16 to Cout (with optional n-split selecting second B / A col offset)
// MODE 1: write fp32 to Cout
// MODE 2: QKV epilogue routing (Q/K per-head layout, V transposed)

template<int MODE>
__global__ __launch_bounds__(256) void gemm_k(
    const u16* __restrict__ A, int lda,
    const u16* __restrict__ BT, int ldb,
    const float* __restrict__ bias, int K,
    const u16* __restrict__ BT2, int nsplit, int acol2,
    void* __restrict__ Cout, int ldc,
    u16* __restrict__ Qr, u16* __restrict__ Kr, u16* __restrict__ Vtr,
    u16* __restrict__ Qc, u16* __restrict__ Kc, u16* __restrict__ Vtc) {
  __shared__ u16 lA[128 * 32];
  __shared__ u16 lB[128 * 32];
  const int tid = threadIdx.x, w = tid >> 6, lane = tid & 63;
  const int quad = lane >> 4, l15 = lane & 15;
  const int m0 = blockIdx.y * 128, n0 = blockIdx.x * 128;
  if (nsplit && n0 >= nsplit) { A += acol2; BT = BT2 - (size_t)nsplit * ldb; }

  const f32x4 z4 = {0.f, 0.f, 0.f, 0.f};
  f32x4 acc[4][4];
#pragma unroll
  for (int i = 0; i < 4; ++i)
#pragma unroll
    for (int j = 0; j < 4; ++j) acc[i][j] = z4;

  const int sr = w * 32 + (lane >> 2);  // staging row (this call); +16 for second
  const int scp = lane & 3;             // staging chunk position within 64B row

  for (int kt = 0; kt < K; kt += 32) {
    int r1 = sr, r2 = sr + 16;
    int c1 = (scp - (r1 >> 2)) & 3;  // swizzled source chunk (2-way-free reads)
    int c2 = (scp - (r2 >> 2)) & 3;
    gld16(A + (size_t)(m0 + r1) * lda + kt + c1 * 8, &lA[r1 * 32 + scp * 8]);
    gld16(A + (size_t)(m0 + r2) * lda + kt + c2 * 8, &lA[r2 * 32 + scp * 8]);
    gld16(BT + (size_t)(n0 + r1) * ldb + kt + c1 * 8, &lB[r1 * 32 + scp * 8]);
    gld16(BT + (size_t)(n0 + r2) * ldb + kt + c2 * 8, &lB[r2 * 32 + scp * 8]);
    __syncthreads();
    short8 af[4], bg[4];
#pragma unroll
    for (int i = 0; i < 4; ++i) {
      int r = (w >> 1) * 64 + i * 16 + l15;
      af[i] = *reinterpret_cast<const short8*>(&lA[r * 32 + ((quad + (r >> 2)) & 3) * 8]);
    }
#pragma unroll
    for (int j = 0; j < 4; ++j) {
      int r = (w & 1) * 64 + j * 16 + l15;
      bg[j] = *reinterpret_cast<const short8*>(&lB[r * 32 + ((quad + (r >> 2)) & 3) * 8]);
    }
#pragma unroll
    for (int i = 0; i < 4; ++i)
#pragma unroll
      for (int j = 0; j < 4; ++j)
        acc[i][j] = __builtin_amdgcn_mfma_f32_16x16x32_bf16(af[i], bg[j], acc[i][j], 0, 0, 0);
    __syncthreads();
  }

#pragma unroll
  for (int i = 0; i < 4; ++i) {
#pragma unroll
    for (int j = 0; j < 4; ++j) {
#pragma unroll
      for (int r = 0; r < 4; ++r) {
        int row = m0 + (w >> 1) * 64 + i * 16 + quad * 4 + r;
        int col = n0 + (w & 1) * 64 + j * 16 + l15;
        float v = acc[i][j][r] + bias[col];
        if (MODE == 0) {
          reinterpret_cast<u16*>(Cout)[(size_t)row * ldc + col] = f2bf(v);
        } else if (MODE == 1) {
          reinterpret_cast<float*>(Cout)[(size_t)row * ldc + col] = v;
        } else {
          int seg = col / 768, cs = col - seg * 768;
          int b = row >> 11, s = row & 2047;
          u16 hv = f2bf(v);
          if (seg == 0) { int h = cs >> 7, d = cs & 127; Qr[((size_t)(b * 6 + h) * 2048 + s) * 128 + d] = hv; }
          else if (seg == 1) { int h = cs >> 7, d = cs & 127; Kr[((size_t)(b * 6 + h) * 2048 + s) * 128 + d] = hv; }
          else if (seg == 2) { int h = cs >> 7, d = cs & 127; Vtr[((size_t)(b * 6 + h) * 128 + d) * 2048 + s] = hv; }
          else if (seg == 3) { int h = cs / 384, d = cs - h * 384; Qc[((size_t)(b * 2 + h) * 2048 + s) * 384 + d] = hv; }
          else if (seg == 4) { int h = cs / 384, d = cs - h * 384; Kc[((size_t)(b * 2 + h) * 2048 + s) * 384 + d] = hv; }
          else               { int h = cs / 384, d = cs - h * 384; Vtc[((size_t)(b * 2 + h) * 384 + d) * 2048 + s] = hv; }
        }
      }
    }
  }
}

// ---------------- flash attention with KV-split ----------------
// Block: 256 threads (4 waves), 64 q-rows (16 per wave), 32-key tiles.
// blockIdx.z = key split; each split covers k_len keys and writes an
// l-normalized bf16 partial O plus per-row (m,l) for the combine pass.
// Q: [bh][S][HD] bf16 (bias+cb folded). K: [bh][S][HD]. Vt: [bh][HD][S].
template<int HD, int CUL>
__global__ __launch_bounds__(256) void attn_k(
    const u16* __restrict__ Qp, const u16* __restrict__ Kp, const u16* __restrict__ Vtp,
    const float* __restrict__ am, const float* __restrict__ cmask,
    u16* __restrict__ Op, float2* __restrict__ Ml,
    int nh, float scale, int k_len) {
  constexpr int CPR = HD / 8;  // 16B chunks per lK row
  __shared__ u16 lK[32 * HD];
  __shared__ u16 lV[HD * 32];
  __shared__ u16 lP[4 * 16 * 32];
  __shared__ float lC[CUL ? 64 * 36 : 4];  // stride 36: quad offset 16 banks -> 2-way (free)

  const int tid = threadIdx.x, w = tid >> 6, lane = tid & 63;
  const int quad = lane >> 4, l15 = lane & 15;
  const int q0 = blockIdx.x * 64;
  const int bh = blockIdx.y;
  const int nbh = gridDim.y;
  const int split = blockIdx.z;
  const int kb = split * k_len;
  const int b = bh / nh;
  const u16* Qb = Qp + ((size_t)bh * S_ + q0) * HD;
  const u16* Kb = Kp + (size_t)bh * S_ * HD;
  const u16* Vb = Vtp + (size_t)bh * HD * S_;
  const float* amb = am + b * S_;
  const float* cmb = CUL ? (cmask + (size_t)b * S_ * S_ + (size_t)q0 * S_) : nullptr;

  // preload Q fragments (A-operand layout)
  short8 qf[HD / 32];
  {
    const u16* qrow = Qb + (size_t)(w * 16 + l15) * HD + quad * 8;
#pragma unroll
    for (int c = 0; c < HD / 32; ++c)
      qf[c] = *reinterpret_cast<const short8*>(qrow + c * 32);
  }
  const f32x4 z4 = {0.f, 0.f, 0.f, 0.f};
  f32x4 O[HD / 16];
#pragma unroll
  for (int j = 0; j < HD / 16; ++j) O[j] = z4;
  float mrow[4], lrow[4];
#pragma unroll
  for (int r = 0; r < 4; ++r) { mrow[r] = -INFINITY; lrow[r] = 0.f; }

  for (int k0 = kb; k0 < kb + k_len; k0 += 32) {
    // stage K tile [32][HD], swizzled within 16-chunk groups
#pragma unroll
    for (int it = 0; it < (4 * HD) / 256; ++it) {
      int idx = it * 256 + tid;
      int n = idx / CPR, cp = idx - n * CPR;
      int c = (cp & ~15) | ((cp - n) & 15);
      gld16(Kb + (size_t)(k0 + n) * HD + c * 8, &lK[idx * 8]);
    }
    // stage Vt tile [HD][32], additive swizzle by n>>2
#pragma unroll
    for (int it = 0; it < (4 * HD) / 256; ++it) {
      int idx = it * 256 + tid;
      int n = idx >> 2, cp = idx & 3;
      int c = (cp - (n >> 2)) & 3;
      gld16(Vb + (size_t)n * S_ + k0 + c * 8, &lV[idx * 8]);
    }
    if (CUL) {
      // padded stride-36 mask tile via regular vector loads
      int row = tid >> 2, cp = tid & 3;
      const float* src = cmb + (size_t)row * S_ + k0 + cp * 8;
      float4 a = *reinterpret_cast<const float4*>(src);
      float4 bq = *reinterpret_cast<const float4*>(src + 4);
      float* dst = &lC[row * 36 + cp * 8];
      *reinterpret_cast<float4*>(dst) = a;
      *reinterpret_cast<float4*>(dst + 4) = bq;
    }
    __syncthreads();

    // S = Q K^T (16 q-rows x 32 keys per wave)
    f32x4 s0 = z4, s1 = z4;
#pragma unroll
    for (int c = 0; c < HD / 32; ++c) {
      int rcp = c * 4 + quad;
      int nA = l15, nB = 16 + l15;
      int swA = (rcp & ~15) | ((rcp + nA) & 15);
      int swB = (rcp & ~15) | ((rcp + nB) & 15);
      short8 b0 = *reinterpret_cast<const short8*>(&lK[(nA * CPR + swA) * 8]);
      short8 b1 = *reinterpret_cast<const short8*>(&lK[(nB * CPR + swB) * 8]);
      s0 = __builtin_amdgcn_mfma_f32_16x16x32_bf16(qf[c], b0, s0, 0, 0, 0);
      s1 = __builtin_amdgcn_mfma_f32_16x16x32_bf16(qf[c], b1, s1, 0, 0, 0);
    }
    float amv0 = amb[k0 + l15];
    float amv1 = amb[k0 + 16 + l15];

    // online softmax + P -> LDS (bf16)
#pragma unroll
    for (int r = 0; r < 4; ++r) {
      int mm = quad * 4 + r;
      float v0 = s0[r] * scale + amv0;
      float v1 = s1[r] * scale + amv1;
      if (CUL) {
        int lrq = w * 16 + mm;
        v0 += lC[lrq * 36 + l15];
        v1 += lC[lrq * 36 + 16 + l15];
      }
      float mx = fmaxf(v0, v1);
      mx = fmaxf(mx, __shfl_xor(mx, 1));
      mx = fmaxf(mx, __shfl_xor(mx, 2));
      mx = fmaxf(mx, __shfl_xor(mx, 4));
      mx = fmaxf(mx, __shfl_xor(mx, 8));
      float mnew = fmaxf(mrow[r], mx);
      float alpha = __expf(mrow[r] - mnew);
      mrow[r] = mnew;
      float p0 = __expf(v0 - mnew);
      float p1 = __expf(v1 - mnew);
      float rs = p0 + p1;
      rs += __shfl_xor(rs, 1);
      rs += __shfl_xor(rs, 2);
      rs += __shfl_xor(rs, 4);
      rs += __shfl_xor(rs, 8);
      lrow[r] = lrow[r] * alpha + rs;
#pragma unroll
      for (int j = 0; j < HD / 16; ++j) O[j][r] *= alpha;
      int wb = w * 512;
      int cA = l15 >> 3, cB = 2 + cA;
      lP[wb + mm * 32 + ((cA + (mm >> 2)) & 3) * 8 + (l15 & 7)] = f2bf(p0);
      lP[wb + mm * 32 + ((cB + (mm >> 2)) & 3) * 8 + (l15 & 7)] = f2bf(p1);
    }

    // O += P V  (P a-frag from per-wave LDS; Vt gives B^T layout)
    short8 pa;
    {
      int m = l15;
      pa = *reinterpret_cast<const short8*>(&lP[w * 512 + m * 32 + ((quad + (m >> 2)) & 3) * 8]);
    }
#pragma unroll
    for (int j = 0; j < HD / 16; ++j) {
      int n = j * 16 + l15;
      short8 bv = *reinterpret_cast<const short8*>(&lV[n * 32 + ((quad + (n >> 2)) & 3) * 8]);
      O[j] = __builtin_amdgcn_mfma_f32_16x16x32_bf16(pa, bv, O[j], 0, 0, 0);
    }
    __syncthreads();
  }

  // epilogue: normalized partial O (bf16) + per-row (m,l)
  const size_t sb = (size_t)split * nbh + bh;
  float invr[4];
#pragma unroll
  for (int r = 0; r < 4; ++r) invr[r] = 1.f / lrow[r];
  u16* op = Op + (sb * S_ + q0) * HD;
#pragma unroll
  for (int j = 0; j < HD / 16; ++j) {
#pragma unroll
    for (int r = 0; r < 4; ++r) {
      int row = w * 16 + quad * 4 + r;
      op[(size_t)row * HD + j * 16 + l15] = f2bf(O[j][r] * invr[r]);
    }
  }
  if (l15 == 0) {
#pragma unroll
    for (int r = 0; r < 4; ++r) {
      int row = w * 16 + quad * 4 + r;
      Ml[sb * S_ + q0 + row] = make_float2(mrow[r], lrow[r]);
    }
  }
}

// ---------------- split combine ----------------
// out[row] = sum_i coef_i * O_i[row] / sum_i coef_i, coef_i = l_i*exp(m_i-m*)
template<int HD>
__global__ __launch_bounds__(256) void combine_k(
    const u16* __restrict__ Op, const float2* __restrict__ Ml,
    u16* __restrict__ AO, int nh, int nbh, int nsplit, int col_off) {
  constexpr int CPR = HD / 8;
  int g = blockIdx.x * 256 + threadIdx.x;
  int row = g / CPR, c = g - row * CPR;
  int bh = row >> 11, s = row & 2047;
  int b = bh / nh, h = bh - b * nh;
  float mi[4], li[4];
  float m = -INFINITY;
  for (int i = 0; i < nsplit; ++i) {
    float2 ml = Ml[((size_t)i * nbh + bh) * S_ + s];
    mi[i] = ml.x; li[i] = ml.y;
    m = fmaxf(m, ml.x);
  }
  float coef[4], wsum = 0.f;
  for (int i = 0; i < nsplit; ++i) { coef[i] = li[i] * __expf(mi[i] - m); wsum += coef[i]; }
  float inv = 1.f / wsum;
  float acc[8];
#pragma unroll
  for (int e = 0; e < 8; ++e) acc[e] = 0.f;
  for (int i = 0; i < nsplit; ++i) {
    short8 ch = *reinterpret_cast<const short8*>(
        Op + (((size_t)i * nbh + bh) * S_ + s) * HD + c * 8);
    float cf = coef[i];
#pragma unroll
    for (int e = 0; e < 8; ++e) acc[e] += cf * bf2f((u16)ch[e]);
  }
  u16 o[8];
#pragma unroll
  for (int e = 0; e < 8; ++e) o[e] = f2bf(acc[e] * inv);
  *reinterpret_cast<uint4*>(AO + ((size_t)(b * S_ + s)) * 1536 + col_off + h * HD + c * 8) =
      *reinterpret_cast<uint4*>(o);
}

// ---------------- launcher ----------------

extern "C" void kernel_launch(void* const* d_in, const int* in_sizes, int n_in,
                              void* d_out, int out_size, void* d_ws, size_t ws_size,
                              hipStream_t stream) {
  const float* x     = (const float*)d_in[0];
  const float* cmask = (const float*)d_in[1];
  const float* amask = (const float*)d_in[2];
  const float* W[8]  = { (const float*)d_in[3], (const float*)d_in[4], (const float*)d_in[5],
                         (const float*)d_in[6], (const float*)d_in[7], (const float*)d_in[8],
                         (const float*)d_in[9], (const float*)d_in[10] };
  const float* rq_b = (const float*)d_in[11];
  const float* rk_b = (const float*)d_in[12];
  const float* rv_b = (const float*)d_in[13];
  const float* ro_b = (const float*)d_in[14];
  const float* cq_b = (const float*)d_in[15];
  const float* ck_b = (const float*)d_in[16];
  const float* cv_b = (const float*)d_in[17];
  const float* co_b = (const float*)d_in[18];
  const float* r_cb = (const float*)d_in[19];
  const float* c_cb = (const float*)d_in[20];
  const float* out_w = (const float*)d_in[21];
  const float* out_b = (const float*)d_in[22];

  char* p = (char*)d_ws;
  auto carve = [&](size_t bytes) -> void* {
    void* r = (void*)p;
    p += (bytes + 255) & ~(size_t)255;
    return r;
  };
  u16* Xb    = (u16*)carve((size_t)BS_ * E_ * 2);       // dead after QKV gemm
  u16* WqkvT = (u16*)carve((size_t)4608 * 768 * 2);     // dead after QKV gemm
  u16* roT   = (u16*)carve((size_t)768 * 768 * 2);
  u16* coT   = (u16*)carve((size_t)768 * 768 * 2);
  u16* outwT = (u16*)carve((size_t)768 * 1536 * 2);
  float* bqkv  = (float*)carve(4608 * 4);
  float* bproj = (float*)carve(1536 * 4);
  u16* Qr  = (u16*)carve((size_t)B_ * 6 * S_ * 128 * 2);
  u16* Kr  = (u16*)carve((size_t)B_ * 6 * S_ * 128 * 2);
  u16* Vtr = (u16*)carve((size_t)B_ * 6 * S_ * 128 * 2);
  u16* Qc  = (u16*)carve((size_t)B_ * 2 * S_ * 384 * 2);
  u16* Kc  = (u16*)carve((size_t)B_ * 2 * S_ * 384 * 2);
  u16* Vtc = (u16*)carve((size_t)B_ * 2 * S_ * 384 * 2);
  u16* AO  = (u16*)carve((size_t)BS_ * 1536 * 2);
  u16* OPc = (u16*)carve((size_t)4 * 4 * S_ * 384 * 2); // cultural partials (4 splits)
  float2* MLr = (float2*)carve((size_t)2 * 12 * S_ * sizeof(float2));
  float2* MLc = (float2*)carve((size_t)4 * 4 * S_ * sizeof(float2));
  // aliases (sequential-stream safe):
  u16* OPr = Xb;        // 12.58MB fits in Xb+WqkvT (13.37MB), both dead by then
  u16* PR  = OPc;       // proj output written after OPc consumed by combine

  conv_x_k<<<dim3(BS_ * E_ / 4 / 256), 256, 0, stream>>>(x, Xb, BS_ * E_ / 4);
  bias_k<<<dim3(24), 256, 0, stream>>>(rq_b, rk_b, rv_b, cq_b, ck_b, cv_b,
                                       ro_b, co_b, r_cb, c_cb, bqkv, bproj);

  TP tp;
  const int wsel[6] = {0, 1, 2, 4, 5, 6};  // rq rk rv cq ck cv
  for (int i = 0; i < 6; ++i) {
    tp.src[i] = W[wsel[i]];
    tp.dst[i] = WqkvT + (size_t)i * 768 * 768;
    tp.rows[i] = 768;
  }
  tp.src[6] = W[3]; tp.dst[6] = roT;   tp.rows[6] = 768;   // ro_w
  tp.src[7] = W[7]; tp.dst[7] = coT;   tp.rows[7] = 768;   // co_w
  tp.src[8] = out_w; tp.dst[8] = outwT; tp.rows[8] = 1536; // out_w
  transpose_k<<<dim3(24, 48, 9), 256, 0, stream>>>(tp);

  // fused QKV projection for both branches (N = 6*768)
  gemm_k<2><<<dim3(36, 32), 256, 0, stream>>>(
      Xb, 768, WqkvT, 768, bqkv, 768,
      (const u16*)nullptr, 0, 0, (void*)nullptr, 0,
      Qr, Kr, Vtr, Qc, Kc, Vtc);

  // flash attention, KV-split: regular x2 (768 blocks), cultural x4 (512 blocks)
  attn_k<128, 0><<<dim3(32, 12, 2), 256, 0, stream>>>(
      Qr, Kr, Vtr, amask, (const float*)nullptr, OPr, MLr, 6, 0.08838834764831845f, 1024);
  attn_k<384, 1><<<dim3(32, 4, 4), 256, 0, stream>>>(
      Qc, Kc, Vtc, amask, cmask, OPc, MLc, 2, 0.05103103630798288f, 512);

  combine_k<128><<<dim3(12 * S_ * 16 / 256), 256, 0, stream>>>(OPr, MLr, AO, 6, 12, 2, 0);
  combine_k<384><<<dim3(4 * S_ * 48 / 256), 256, 0, stream>>>(OPc, MLc, AO, 2, 4, 4, 768);

  // merged per-branch output projections (block-diagonal select on n)
  gemm_k<0><<<dim3(12, 32), 256, 0, stream>>>(
      AO, 1536, roT, 768, bproj, 768,
      coT, 768, 768, (void*)PR, 1536,
      nullptr, nullptr, nullptr, nullptr, nullptr, nullptr);

  // final: PR[4096,1536] @ out_w + out_b -> fp32 d_out
  gemm_k<1><<<dim3(6, 32), 256, 0, stream>>>(
      PR, 1536, outwT, 1536, out_b, 1536,
      (const u16*)nullptr, 0, 0, d_out, 768,
      nullptr, nullptr, nullptr, nullptr, nullptr, nullptr);
}

// Round 3
// 471.924 us; speedup vs baseline: 1.2925x; 1.0259x over previous
//
#include <hip/hip_runtime.h>
#include <hip/hip_bf16.h>

using u16 = unsigned short;
using u32 = unsigned int;
typedef short short8 __attribute__((ext_vector_type(8)));
typedef float f32x4 __attribute__((ext_vector_type(4)));

#define B_  2
#define S_  2048
#define E_  768
#define BS_ 4096

#define L2E_ 1.44269504088896f
#define FML2_ 17.3123404906676f   // 12.0 * log2(e) fixed softmax stabilizer

__device__ __forceinline__ u16 f2bf(float f) {
  __hip_bfloat16 h = __float2bfloat16(f);
  return *reinterpret_cast<u16*>(&h);
}

__device__ __forceinline__ float bf2f(u16 b) {
  u32 bits = (u32)b << 16;
  return *reinterpret_cast<float*>(&bits);
}

// async global->LDS, 16B per lane. LDS dest must be wave-uniform base + lane*16.
__device__ __forceinline__ void gld16(const void* g, void* l) {
  __builtin_amdgcn_global_load_lds(
      (const __attribute__((address_space(1))) u32*)g,
      (__attribute__((address_space(3))) u32*)l, 16, 0, 0);
}

// ---------------- conversion / misc kernels ----------------

__global__ __launch_bounds__(256) void conv_x_k(const float* __restrict__ x,
                                                u16* __restrict__ xb, int n4) {
  int i = blockIdx.x * 256 + threadIdx.x;
  if (i >= n4) return;
  float4 v = reinterpret_cast<const float4*>(x)[i];
  u32 lo = (u32)f2bf(v.x) | ((u32)f2bf(v.y) << 16);
  u32 hi = (u32)f2bf(v.z) | ((u32)f2bf(v.w) << 16);
  reinterpret_cast<uint2*>(xb)[i] = make_uint2(lo, hi);
}

__global__ __launch_bounds__(256) void bias_k(
    const float* rqb, const float* rkb, const float* rvb,
    const float* cqb, const float* ckb, const float* cvb,
    const float* rob, const float* cob,
    const float* rcb, const float* ccb,
    float* bqkv, float* bproj) {
  int t = blockIdx.x * 256 + threadIdx.x;
  if (t < 4608) {
    int seg = t / 768, i = t - seg * 768;
    float v = 0.f;
    if      (seg == 0) v = rqb[i] + rcb[i];   // cultural bias folds into Q bias
    else if (seg == 1) v = rkb[i];
    else if (seg == 2) v = rvb[i];
    else if (seg == 3) v = cqb[i] + ccb[i];
    else if (seg == 4) v = ckb[i];
    else               v = cvb[i];
    bqkv[t] = v;
  } else {
    int u = t - 4608;
    if (u < 1536) bproj[u] = (u < 768) ? rob[u] : cob[u - 768];
  }
}

struct TP {
  const float* src[9];
  u16* dst[9];
  int rows[9];
};

// dst[c][r] = bf16(src[r][c]); src is [rows][768]
__global__ __launch_bounds__(256) void transpose_k(TP p) {
  int mi = blockIdx.z;
  int rows = p.rows[mi];
  int r0 = blockIdx.y * 32;
  if (r0 >= rows) return;
  int c0 = blockIdx.x * 32;
  const float* src = p.src[mi];
  u16* dst = p.dst[mi];
  __shared__ float t[32][33];
  int tx = threadIdx.x & 31, ty = threadIdx.x >> 5;
#pragma unroll
  for (int d = 0; d < 4; ++d) {
    int r = ty + d * 8;
    t[r][tx] = src[(size_t)(r0 + r) * 768 + c0 + tx];
  }
  __syncthreads();
#pragma unroll
  for (int d = 0; d < 4; ++d) {
    int c = ty + d * 8;
    dst[(size_t)(c0 + c) * rows + r0 + tx] = f2bf(t[tx][c]);
  }
}

// ---------------- generic GEMM: C[M,N] = A[M,K] * BT[N,K]^T + bias ----------------
// MODE 0: write bf16 to Cout (with optional n-split selecting second B / A col offset)
// MODE 1: write fp32 to Cout
// MODE 2: QKV epilogue routing (Q/K per-head layout, V transposed)

template<int MODE>
__global__ __launch_bounds__(256) void gemm_k(
    const u16* __restrict__ A, int lda,
    const u16* __restrict__ BT, int ldb,
    const float* __restrict__ bias, int K,
    const u16* __restrict__ BT2, int nsplit, int acol2,
    void* __restrict__ Cout, int ldc,
    u16* __restrict__ Qr, u16* __restrict__ Kr, u16* __restrict__ Vtr,
    u16* __restrict__ Qc, u16* __restrict__ Kc, u16* __restrict__ Vtc) {
  __shared__ u16 lA[128 * 32];
  __shared__ u16 lB[128 * 32];
  const int tid = threadIdx.x, w = tid >> 6, lane = tid & 63;
  const int quad = lane >> 4, l15 = lane & 15;
  const int m0 = blockIdx.y * 128, n0 = blockIdx.x * 128;
  if (nsplit && n0 >= nsplit) { A += acol2; BT = BT2 - (size_t)nsplit * ldb; }

  const f32x4 z4 = {0.f, 0.f, 0.f, 0.f};
  f32x4 acc[4][4];
#pragma unroll
  for (int i = 0; i < 4; ++i)
#pragma unroll
    for (int j = 0; j < 4; ++j) acc[i][j] = z4;

  const int sr = w * 32 + (lane >> 2);  // staging row (this call); +16 for second
  const int scp = lane & 3;             // staging chunk position within 64B row

  for (int kt = 0; kt < K; kt += 32) {
    int r1 = sr, r2 = sr + 16;
    int c1 = (scp - (r1 >> 2)) & 3;  // swizzled source chunk (2-way-free reads)
    int c2 = (scp - (r2 >> 2)) & 3;
    gld16(A + (size_t)(m0 + r1) * lda + kt + c1 * 8, &lA[r1 * 32 + scp * 8]);
    gld16(A + (size_t)(m0 + r2) * lda + kt + c2 * 8, &lA[r2 * 32 + scp * 8]);
    gld16(BT + (size_t)(n0 + r1) * ldb + kt + c1 * 8, &lB[r1 * 32 + scp * 8]);
    gld16(BT + (size_t)(n0 + r2) * ldb + kt + c2 * 8, &lB[r2 * 32 + scp * 8]);
    __syncthreads();
    short8 af[4], bg[4];
#pragma unroll
    for (int i = 0; i < 4; ++i) {
      int r = (w >> 1) * 64 + i * 16 + l15;
      af[i] = *reinterpret_cast<const short8*>(&lA[r * 32 + ((quad + (r >> 2)) & 3) * 8]);
    }
#pragma unroll
    for (int j = 0; j < 4; ++j) {
      int r = (w & 1) * 64 + j * 16 + l15;
      bg[j] = *reinterpret_cast<const short8*>(&lB[r * 32 + ((quad + (r >> 2)) & 3) * 8]);
    }
#pragma unroll
    for (int i = 0; i < 4; ++i)
#pragma unroll
      for (int j = 0; j < 4; ++j)
        acc[i][j] = __builtin_amdgcn_mfma_f32_16x16x32_bf16(af[i], bg[j], acc[i][j], 0, 0, 0);
    __syncthreads();
  }

#pragma unroll
  for (int i = 0; i < 4; ++i) {
#pragma unroll
    for (int j = 0; j < 4; ++j) {
#pragma unroll
      for (int r = 0; r < 4; ++r) {
        int row = m0 + (w >> 1) * 64 + i * 16 + quad * 4 + r;
        int col = n0 + (w & 1) * 64 + j * 16 + l15;
        float v = acc[i][j][r] + bias[col];
        if (MODE == 0) {
          reinterpret_cast<u16*>(Cout)[(size_t)row * ldc + col] = f2bf(v);
        } else if (MODE == 1) {
          reinterpret_cast<float*>(Cout)[(size_t)row * ldc + col] = v;
        } else {
          int seg = col / 768, cs = col - seg * 768;
          int b = row >> 11, s = row & 2047;
          u16 hv = f2bf(v);
          if (seg == 0) { int h = cs >> 7, d = cs & 127; Qr[((size_t)(b * 6 + h) * 2048 + s) * 128 + d] = hv; }
          else if (seg == 1) { int h = cs >> 7, d = cs & 127; Kr[((size_t)(b * 6 + h) * 2048 + s) * 128 + d] = hv; }
          else if (seg == 2) { int h = cs >> 7, d = cs & 127; Vtr[((size_t)(b * 6 + h) * 128 + d) * 2048 + s] = hv; }
          else if (seg == 3) { int h = cs / 384, d = cs - h * 384; Qc[((size_t)(b * 2 + h) * 2048 + s) * 384 + d] = hv; }
          else if (seg == 4) { int h = cs / 384, d = cs - h * 384; Kc[((size_t)(b * 2 + h) * 2048 + s) * 384 + d] = hv; }
          else               { int h = cs / 384, d = cs - h * 384; Vtc[((size_t)(b * 2 + h) * 384 + d) * 2048 + s] = hv; }
        }
      }
    }
  }
}

// ---------------- flash attention, fixed-max softmax, KV-split ----------------
// Block: 256 threads (4 waves), 64 q-rows (16 per wave), 32-key tiles.
// Fixed stabilizer (no online max): p = exp2(score*log2e - FML2_).
// Row-sum l computed by an extra MFMA vs a constant ones B-fragment.
// Each split writes l-normalized bf16 partial O + per-row l.
template<int HD, int CUL>
__global__ __launch_bounds__(256) void attn_k(
    const u16* __restrict__ Qp, const u16* __restrict__ Kp, const u16* __restrict__ Vtp,
    const float* __restrict__ am, const float* __restrict__ cmask,
    u16* __restrict__ Op, float* __restrict__ Ls,
    int nh, float scaleL2E, int k_len) {
  constexpr int CPR = HD / 8;  // 16B chunks per lK row
  __shared__ u16 lK[32 * HD];
  __shared__ u16 lV[HD * 32];
  __shared__ u16 lP[4 * 16 * 32];
  __shared__ float lC[CUL ? 64 * 36 : 4];  // stride 36: quad offset 16 banks -> 2-way (free)

  const int tid = threadIdx.x, w = tid >> 6, lane = tid & 63;
  const int quad = lane >> 4, l15 = lane & 15;
  const int q0 = blockIdx.x * 64;
  const int bh = blockIdx.y;
  const int nbh = gridDim.y;
  const int split = blockIdx.z;
  const int kb = split * k_len;
  const int b = bh / nh;
  const u16* Qb = Qp + ((size_t)bh * S_ + q0) * HD;
  const u16* Kb = Kp + (size_t)bh * S_ * HD;
  const u16* Vb = Vtp + (size_t)bh * HD * S_;
  const float* amb = am + b * S_;
  const float* cmb = CUL ? (cmask + (size_t)b * S_ * S_ + (size_t)q0 * S_) : nullptr;

  // preload Q fragments (A-operand layout)
  short8 qf[HD / 32];
  {
    const u16* qrow = Qb + (size_t)(w * 16 + l15) * HD + quad * 8;
#pragma unroll
    for (int c = 0; c < HD / 32; ++c)
      qf[c] = *reinterpret_cast<const short8*>(qrow + c * 32);
  }
  // constant ones B-fragment: B[n=0][k]=1 else 0 -> D col0 = row-sum of P
  short8 ob;
  {
    short ov = (l15 == 0) ? (short)0x3F80 : (short)0;
#pragma unroll
    for (int e = 0; e < 8; ++e) ob[e] = ov;
  }
  const f32x4 z4 = {0.f, 0.f, 0.f, 0.f};
  f32x4 O[HD / 16];
#pragma unroll
  for (int j = 0; j < HD / 16; ++j) O[j] = z4;
  f32x4 Lacc = z4;

  for (int k0 = kb; k0 < kb + k_len; k0 += 32) {
    // stage K tile [32][HD], swizzled within 16-chunk groups
#pragma unroll
    for (int it = 0; it < (4 * HD) / 256; ++it) {
      int idx = it * 256 + tid;
      int n = idx / CPR, cp = idx - n * CPR;
      int c = (cp & ~15) | ((cp - n) & 15);
      gld16(Kb + (size_t)(k0 + n) * HD + c * 8, &lK[idx * 8]);
    }
    // stage Vt tile [HD][32], additive swizzle by n>>2
#pragma unroll
    for (int it = 0; it < (4 * HD) / 256; ++it) {
      int idx = it * 256 + tid;
      int n = idx >> 2, cp = idx & 3;
      int c = (cp - (n >> 2)) & 3;
      gld16(Vb + (size_t)n * S_ + k0 + c * 8, &lV[idx * 8]);
    }
    if (CUL) {
      // padded stride-36 mask tile, pre-scaled by log2(e)
      int row = tid >> 2, cp = tid & 3;
      const float* src = cmb + (size_t)row * S_ + k0 + cp * 8;
      float4 a = *reinterpret_cast<const float4*>(src);
      float4 bq = *reinterpret_cast<const float4*>(src + 4);
      float* dst = &lC[row * 36 + cp * 8];
      dst[0] = a.x * L2E_; dst[1] = a.y * L2E_; dst[2] = a.z * L2E_; dst[3] = a.w * L2E_;
      dst[4] = bq.x * L2E_; dst[5] = bq.y * L2E_; dst[6] = bq.z * L2E_; dst[7] = bq.w * L2E_;
    }
    __syncthreads();

    // S = Q K^T (16 q-rows x 32 keys per wave)
    f32x4 s0 = z4, s1 = z4;
#pragma unroll
    for (int c = 0; c < HD / 32; ++c) {
      int rcp = c * 4 + quad;
      int nA = l15, nB = 16 + l15;
      int swA = (rcp & ~15) | ((rcp + nA) & 15);
      int swB = (rcp & ~15) | ((rcp + nB) & 15);
      short8 b0 = *reinterpret_cast<const short8*>(&lK[(nA * CPR + swA) * 8]);
      short8 b1 = *reinterpret_cast<const short8*>(&lK[(nB * CPR + swB) * 8]);
      s0 = __builtin_amdgcn_mfma_f32_16x16x32_bf16(qf[c], b0, s0, 0, 0, 0);
      s1 = __builtin_amdgcn_mfma_f32_16x16x32_bf16(qf[c], b1, s1, 0, 0, 0);
    }
    float pre0 = fmaf(amb[k0 + l15], L2E_, -FML2_);
    float pre1 = fmaf(amb[k0 + 16 + l15], L2E_, -FML2_);

    // fixed-max softmax: p = exp2(s*scaleL2E + pre (+ cm*l2e)) -> P in LDS (bf16)
#pragma unroll
    for (int r = 0; r < 4; ++r) {
      int mm = quad * 4 + r;
      float v0 = fmaf(s0[r], scaleL2E, pre0);
      float v1 = fmaf(s1[r], scaleL2E, pre1);
      if (CUL) {
        int lrq = w * 16 + mm;
        v0 += lC[lrq * 36 + l15];
        v1 += lC[lrq * 36 + 16 + l15];
      }
      float p0 = exp2f(v0);
      float p1 = exp2f(v1);
      int wb = w * 512;
      int cA = l15 >> 3, cB = 2 + cA;
      lP[wb + mm * 32 + ((cA + (mm >> 2)) & 3) * 8 + (l15 & 7)] = f2bf(p0);
      lP[wb + mm * 32 + ((cB + (mm >> 2)) & 3) * 8 + (l15 & 7)] = f2bf(p1);
    }

    // O += P V  (P a-frag from per-wave LDS; Vt gives B^T layout); l via ones-MFMA
    short8 pa;
    {
      int m = l15;
      pa = *reinterpret_cast<const short8*>(&lP[w * 512 + m * 32 + ((quad + (m >> 2)) & 3) * 8]);
    }
    Lacc = __builtin_amdgcn_mfma_f32_16x16x32_bf16(pa, ob, Lacc, 0, 0, 0);
#pragma unroll
    for (int j = 0; j < HD / 16; ++j) {
      int n = j * 16 + l15;
      short8 bv = *reinterpret_cast<const short8*>(&lV[n * 32 + ((quad + (n >> 2)) & 3) * 8]);
      O[j] = __builtin_amdgcn_mfma_f32_16x16x32_bf16(pa, bv, O[j], 0, 0, 0);
    }
    __syncthreads();
  }

  // epilogue: broadcast row-sums (col 0 of Lacc lives in lane quad*16), normalize
  const size_t sb = (size_t)split * nbh + bh;
  float invr[4];
#pragma unroll
  for (int r = 0; r < 4; ++r) {
    float lv = __shfl(Lacc[r], lane & 48);
    invr[r] = 1.f / lv;
  }
  u16* op = Op + (sb * S_ + q0) * HD;
#pragma unroll
  for (int j = 0; j < HD / 16; ++j) {
#pragma unroll
    for (int r = 0; r < 4; ++r) {
      int row = w * 16 + quad * 4 + r;
      op[(size_t)row * HD + j * 16 + l15] = f2bf(O[j][r] * invr[r]);
    }
  }
  if (l15 == 0) {
#pragma unroll
    for (int r = 0; r < 4; ++r) {
      int row = w * 16 + quad * 4 + r;
      Ls[sb * S_ + q0 + row] = Lacc[r];
    }
  }
}

// ---------------- split combine ----------------
// out[row] = sum_i l_i * O_i[row] / sum_i l_i  (fixed max -> no exp needed)
template<int HD>
__global__ __launch_bounds__(256) void combine_k(
    const u16* __restrict__ Op, const float* __restrict__ Ls,
    u16* __restrict__ AO, int nh, int nbh, int nsplit, int col_off) {
  constexpr int CPR = HD / 8;
  int g = blockIdx.x * 256 + threadIdx.x;
  int row = g / CPR, c = g - row * CPR;
  int bh = row >> 11, s = row & 2047;
  int b = bh / nh, h = bh - b * nh;
  float li[8];
  float wsum = 0.f;
  for (int i = 0; i < nsplit; ++i) {
    li[i] = Ls[((size_t)i * nbh + bh) * S_ + s];
    wsum += li[i];
  }
  float inv = 1.f / wsum;
  float acc[8];
#pragma unroll
  for (int e = 0; e < 8; ++e) acc[e] = 0.f;
  for (int i = 0; i < nsplit; ++i) {
    short8 ch = *reinterpret_cast<const short8*>(
        Op + (((size_t)i * nbh + bh) * S_ + s) * HD + c * 8);
    float cf = li[i];
#pragma unroll
    for (int e = 0; e < 8; ++e) acc[e] += cf * bf2f((u16)ch[e]);
  }
  u16 o[8];
#pragma unroll
  for (int e = 0; e < 8; ++e) o[e] = f2bf(acc[e] * inv);
  *reinterpret_cast<uint4*>(AO + ((size_t)(b * S_ + s)) * 1536 + col_off + h * HD + c * 8) =
      *reinterpret_cast<uint4*>(o);
}

// ---------------- launcher ----------------

extern "C" void kernel_launch(void* const* d_in, const int* in_sizes, int n_in,
                              void* d_out, int out_size, void* d_ws, size_t ws_size,
                              hipStream_t stream) {
  const float* x     = (const float*)d_in[0];
  const float* cmask = (const float*)d_in[1];
  const float* amask = (const float*)d_in[2];
  const float* W[8]  = { (const float*)d_in[3], (const float*)d_in[4], (const float*)d_in[5],
                         (const float*)d_in[6], (const float*)d_in[7], (const float*)d_in[8],
                         (const float*)d_in[9], (const float*)d_in[10] };
  const float* rq_b = (const float*)d_in[11];
  const float* rk_b = (const float*)d_in[12];
  const float* rv_b = (const float*)d_in[13];
  const float* ro_b = (const float*)d_in[14];
  const float* cq_b = (const float*)d_in[15];
  const float* ck_b = (const float*)d_in[16];
  const float* cv_b = (const float*)d_in[17];
  const float* co_b = (const float*)d_in[18];
  const float* r_cb = (const float*)d_in[19];
  const float* c_cb = (const float*)d_in[20];
  const float* out_w = (const float*)d_in[21];
  const float* out_b = (const float*)d_in[22];

  char* p = (char*)d_ws;
  auto carve = [&](size_t bytes) -> void* {
    void* r = (void*)p;
    p += (bytes + 255) & ~(size_t)255;
    return r;
  };
  u16* Xb    = (u16*)carve((size_t)BS_ * E_ * 2);       // dead after QKV gemm
  u16* WqkvT = (u16*)carve((size_t)4608 * 768 * 2);     // dead after QKV gemm
  u16* roT   = (u16*)carve((size_t)768 * 768 * 2);
  u16* coT   = (u16*)carve((size_t)768 * 768 * 2);
  u16* outwT = (u16*)carve((size_t)768 * 1536 * 2);
  float* bqkv  = (float*)carve(4608 * 4);
  float* bproj = (float*)carve(1536 * 4);
  u16* Qr  = (u16*)carve((size_t)B_ * 6 * S_ * 128 * 2);
  u16* Kr  = (u16*)carve((size_t)B_ * 6 * S_ * 128 * 2);
  u16* Vtr = (u16*)carve((size_t)B_ * 6 * S_ * 128 * 2);
  u16* Qc  = (u16*)carve((size_t)B_ * 2 * S_ * 384 * 2);
  u16* Kc  = (u16*)carve((size_t)B_ * 2 * S_ * 384 * 2);
  u16* Vtc = (u16*)carve((size_t)B_ * 2 * S_ * 384 * 2);
  u16* AO  = (u16*)carve((size_t)BS_ * 1536 * 2);

  // split counts chosen by available workspace (constant across calls ->
  // graph-capture safe). Plan A: reg x4 / cul x8. Plan B (round-2 footprint):
  // reg x2 (partials alias dead Xb+WqkvT) / cul x4.
  size_t used = (size_t)(p - (char*)d_ws);
  size_t rem = (ws_size > used) ? (ws_size - used) : 0;
  const size_t oprA = (size_t)4 * 12 * S_ * 128 * 2;   // 25.2 MB
  const size_t opcA = (size_t)8 * 4 * S_ * 384 * 2;    // 50.3 MB
  const size_t opcB = (size_t)4 * 4 * S_ * 384 * 2;    // 25.2 MB
  int SPR, SPC;
  u16 *OPr, *OPc;
  float *Lr, *Lc;
  if (rem >= oprA + opcA + (size_t)4 * 12 * S_ * 4 + (size_t)8 * 4 * S_ * 4 + 4096) {
    SPR = 4; SPC = 8;
    OPr = (u16*)carve(oprA);
    OPc = (u16*)carve(opcA);
    Lr  = (float*)carve((size_t)SPR * 12 * S_ * 4);
    Lc  = (float*)carve((size_t)SPC * 4 * S_ * 4);
  } else {
    SPR = 2; SPC = 4;
    OPc = (u16*)carve(opcB);
    Lr  = (float*)carve((size_t)SPR * 12 * S_ * 4);
    Lc  = (float*)carve((size_t)SPC * 4 * S_ * 4);
    OPr = Xb;  // 12.58 MB fits in dead Xb+WqkvT region (13.37 MB)
  }
  u16* PR = OPc;  // proj output written after OPc consumed by combine

  conv_x_k<<<dim3(BS_ * E_ / 4 / 256), 256, 0, stream>>>(x, Xb, BS_ * E_ / 4);
  bias_k<<<dim3(24), 256, 0, stream>>>(rq_b, rk_b, rv_b, cq_b, ck_b, cv_b,
                                       ro_b, co_b, r_cb, c_cb, bqkv, bproj);

  TP tp;
  const int wsel[6] = {0, 1, 2, 4, 5, 6};  // rq rk rv cq ck cv
  for (int i = 0; i < 6; ++i) {
    tp.src[i] = W[wsel[i]];
    tp.dst[i] = WqkvT + (size_t)i * 768 * 768;
    tp.rows[i] = 768;
  }
  tp.src[6] = W[3]; tp.dst[6] = roT;   tp.rows[6] = 768;   // ro_w
  tp.src[7] = W[7]; tp.dst[7] = coT;   tp.rows[7] = 768;   // co_w
  tp.src[8] = out_w; tp.dst[8] = outwT; tp.rows[8] = 1536; // out_w
  transpose_k<<<dim3(24, 48, 9), 256, 0, stream>>>(tp);

  // fused QKV projection for both branches (N = 6*768)
  gemm_k<2><<<dim3(36, 32), 256, 0, stream>>>(
      Xb, 768, WqkvT, 768, bqkv, 768,
      (const u16*)nullptr, 0, 0, (void*)nullptr, 0,
      Qr, Kr, Vtr, Qc, Kc, Vtc);

  // flash attention, fixed-max, KV-split
  attn_k<128, 0><<<dim3(32, 12, SPR), 256, 0, stream>>>(
      Qr, Kr, Vtr, amask, (const float*)nullptr, OPr, Lr, 6,
      0.08838834764831845f * L2E_, S_ / SPR);
  attn_k<384, 1><<<dim3(32, 4, SPC), 256, 0, stream>>>(
      Qc, Kc, Vtc, amask, cmask, OPc, Lc, 2,
      0.05103103630798288f * L2E_, S_ / SPC);

  combine_k<128><<<dim3(12 * S_ * 16 / 256), 256, 0, stream>>>(OPr, Lr, AO, 6, 12, SPR, 0);
  combine_k<384><<<dim3(4 * S_ * 48 / 256), 256, 0, stream>>>(OPc, Lc, AO, 2, 4, SPC, 768);

  // merged per-branch output projections (block-diagonal select on n)
  gemm_k<0><<<dim3(12, 32), 256, 0, stream>>>(
      AO, 1536, roT, 768, bproj, 768,
      coT, 768, 768, (void*)PR, 1536,
      nullptr, nullptr, nullptr, nullptr, nullptr, nullptr);

  // final: PR[4096,1536] @ out_w + out_b -> fp32 d_out
  gemm_k<1><<<dim3(6, 32), 256, 0, stream>>>(
      PR, 1536, outwT, 1536, out_b, 1536,
      (const u16*)nullptr, 0, 0, d_out, 768,
      nullptr, nullptr, nullptr, nullptr, nullptr, nullptr);
}

// Round 4
// 461.203 us; speedup vs baseline: 1.3226x; 1.0232x over previous
//
#include <hip/hip_runtime.h>
#include <hip/hip_bf16.h>

using u16 = unsigned short;
using u32 = unsigned int;
typedef short short8 __attribute__((ext_vector_type(8)));
typedef float f32x4 __attribute__((ext_vector_type(4)));

#define B_  2
#define S_  2048
#define E_  768
#define BS_ 4096

#define L2E_ 1.44269504088896f
#define FML2_ 17.3123404906676f   // 12.0 * log2(e) fixed softmax stabilizer

__device__ __forceinline__ u16 f2bf(float f) {
  __hip_bfloat16 h = __float2bfloat16(f);
  return *reinterpret_cast<u16*>(&h);
}

// async global->LDS, 16B per lane. LDS dest must be wave-uniform base + lane*16.
__device__ __forceinline__ void gld16(const void* g, void* l) {
  __builtin_amdgcn_global_load_lds(
      (const __attribute__((address_space(1))) u32*)g,
      (__attribute__((address_space(3))) u32*)l, 16, 0, 0);
}

// ---------------- conversion / misc kernels ----------------

__global__ __launch_bounds__(256) void conv_x_k(const float* __restrict__ x,
                                                u16* __restrict__ xb, int n4) {
  int i = blockIdx.x * 256 + threadIdx.x;
  if (i >= n4) return;
  float4 v = reinterpret_cast<const float4*>(x)[i];
  u32 lo = (u32)f2bf(v.x) | ((u32)f2bf(v.y) << 16);
  u32 hi = (u32)f2bf(v.z) | ((u32)f2bf(v.w) << 16);
  reinterpret_cast<uint2*>(xb)[i] = make_uint2(lo, hi);
}

__global__ __launch_bounds__(256) void bias_k(
    const float* rqb, const float* rkb, const float* rvb,
    const float* cqb, const float* ckb, const float* cvb,
    const float* rob, const float* cob,
    const float* rcb, const float* ccb,
    float* bqkv, float* bproj) {
  int t = blockIdx.x * 256 + threadIdx.x;
  if (t < 4608) {
    int seg = t / 768, i = t - seg * 768;
    float v = 0.f;
    if      (seg == 0) v = rqb[i] + rcb[i];   // cultural bias folds into Q bias
    else if (seg == 1) v = rkb[i];
    else if (seg == 2) v = rvb[i];
    else if (seg == 3) v = cqb[i] + ccb[i];
    else if (seg == 4) v = ckb[i];
    else               v = cvb[i];
    bqkv[t] = v;
  } else {
    int u = t - 4608;
    if (u < 1536) bproj[u] = (u < 768) ? rob[u] : cob[u - 768];
  }
}

struct TP {
  const float* src[9];
  u16* dst[9];
  int rows[9];
};

// dst[c][r] = bf16(src[r][c]); src is [rows][768]
__global__ __launch_bounds__(256) void transpose_k(TP p) {
  int mi = blockIdx.z;
  int rows = p.rows[mi];
  int r0 = blockIdx.y * 32;
  if (r0 >= rows) return;
  int c0 = blockIdx.x * 32;
  const float* src = p.src[mi];
  u16* dst = p.dst[mi];
  __shared__ float t[32][33];
  int tx = threadIdx.x & 31, ty = threadIdx.x >> 5;
#pragma unroll
  for (int d = 0; d < 4; ++d) {
    int r = ty + d * 8;
    t[r][tx] = src[(size_t)(r0 + r) * 768 + c0 + tx];
  }
  __syncthreads();
#pragma unroll
  for (int d = 0; d < 4; ++d) {
    int c = ty + d * 8;
    dst[(size_t)(c0 + c) * rows + r0 + tx] = f2bf(t[tx][c]);
  }
}

// ---------------- generic GEMM: C[M,N] = A[M,K] * BT[N,K]^T + bias ----------------
// MODE 0: write bf16 to Cout (with optional n-split selecting second B / A col offset)
// MODE 1: write fp32 to Cout
// MODE 2: QKV epilogue routing (Q/K per-head layout, V transposed)

template<int MODE>
__global__ __launch_bounds__(256) void gemm_k(
    const u16* __restrict__ A, int lda,
    const u16* __restrict__ BT, int ldb,
    const float* __restrict__ bias, int K,
    const u16* __restrict__ BT2, int nsplit, int acol2,
    void* __restrict__ Cout, int ldc,
    u16* __restrict__ Qr, u16* __restrict__ Kr, u16* __restrict__ Vtr,
    u16* __restrict__ Qc, u16* __restrict__ Kc, u16* __restrict__ Vtc) {
  __shared__ u16 lA[128 * 32];
  __shared__ u16 lB[128 * 32];
  const int tid = threadIdx.x, w = tid >> 6, lane = tid & 63;
  const int quad = lane >> 4, l15 = lane & 15;
  const int m0 = blockIdx.y * 128, n0 = blockIdx.x * 128;
  if (nsplit && n0 >= nsplit) { A += acol2; BT = BT2 - (size_t)nsplit * ldb; }

  const f32x4 z4 = {0.f, 0.f, 0.f, 0.f};
  f32x4 acc[4][4];
#pragma unroll
  for (int i = 0; i < 4; ++i)
#pragma unroll
    for (int j = 0; j < 4; ++j) acc[i][j] = z4;

  const int sr = w * 32 + (lane >> 2);
  const int scp = lane & 3;

  for (int kt = 0; kt < K; kt += 32) {
    int r1 = sr, r2 = sr + 16;
    int c1 = (scp - (r1 >> 2)) & 3;
    int c2 = (scp - (r2 >> 2)) & 3;
    gld16(A + (size_t)(m0 + r1) * lda + kt + c1 * 8, &lA[r1 * 32 + scp * 8]);
    gld16(A + (size_t)(m0 + r2) * lda + kt + c2 * 8, &lA[r2 * 32 + scp * 8]);
    gld16(BT + (size_t)(n0 + r1) * ldb + kt + c1 * 8, &lB[r1 * 32 + scp * 8]);
    gld16(BT + (size_t)(n0 + r2) * ldb + kt + c2 * 8, &lB[r2 * 32 + scp * 8]);
    __syncthreads();
    short8 af[4], bg[4];
#pragma unroll
    for (int i = 0; i < 4; ++i) {
      int r = (w >> 1) * 64 + i * 16 + l15;
      af[i] = *reinterpret_cast<const short8*>(&lA[r * 32 + ((quad + (r >> 2)) & 3) * 8]);
    }
#pragma unroll
    for (int j = 0; j < 4; ++j) {
      int r = (w & 1) * 64 + j * 16 + l15;
      bg[j] = *reinterpret_cast<const short8*>(&lB[r * 32 + ((quad + (r >> 2)) & 3) * 8]);
    }
#pragma unroll
    for (int i = 0; i < 4; ++i)
#pragma unroll
      for (int j = 0; j < 4; ++j)
        acc[i][j] = __builtin_amdgcn_mfma_f32_16x16x32_bf16(af[i], bg[j], acc[i][j], 0, 0, 0);
    __syncthreads();
  }

#pragma unroll
  for (int i = 0; i < 4; ++i) {
#pragma unroll
    for (int j = 0; j < 4; ++j) {
#pragma unroll
      for (int r = 0; r < 4; ++r) {
        int row = m0 + (w >> 1) * 64 + i * 16 + quad * 4 + r;
        int col = n0 + (w & 1) * 64 + j * 16 + l15;
        float v = acc[i][j][r] + bias[col];
        if (MODE == 0) {
          reinterpret_cast<u16*>(Cout)[(size_t)row * ldc + col] = f2bf(v);
        } else if (MODE == 1) {
          reinterpret_cast<float*>(Cout)[(size_t)row * ldc + col] = v;
        } else {
          int seg = col / 768, cs = col - seg * 768;
          int b = row >> 11, s = row & 2047;
          u16 hv = f2bf(v);
          if (seg == 0) { int h = cs >> 7, d = cs & 127; Qr[((size_t)(b * 6 + h) * 2048 + s) * 128 + d] = hv; }
          else if (seg == 1) { int h = cs >> 7, d = cs & 127; Kr[((size_t)(b * 6 + h) * 2048 + s) * 128 + d] = hv; }
          else if (seg == 2) { int h = cs >> 7, d = cs & 127; Vtr[((size_t)(b * 6 + h) * 128 + d) * 2048 + s] = hv; }
          else if (seg == 3) { int h = cs / 384, d = cs - h * 384; Qc[((size_t)(b * 2 + h) * 2048 + s) * 384 + d] = hv; }
          else if (seg == 4) { int h = cs / 384, d = cs - h * 384; Kc[((size_t)(b * 2 + h) * 2048 + s) * 384 + d] = hv; }
          else               { int h = cs / 384, d = cs - h * 384; Vtc[((size_t)(b * 2 + h) * 384 + d) * 2048 + s] = hv; }
        }
      }
    }
  }
}

// ---------------- attention as two GEMMs (fixed-max softmax) ----------------
// g1: P[bh][S][S] = exp2(QK^T*scale + am (+cm) - M), bf16; Lp[gz][32][S] = per-
//     64-col partial row sums (fp32, computed in-epilogue, 4 shfl per row).
// gz = zoff + blockIdx.z; gz<12 = regular head (K=128), else cultural (K=384).
__global__ __launch_bounds__(256) void attn_g1_k(
    const u16* __restrict__ Qr, const u16* __restrict__ Kr,
    const u16* __restrict__ Qc, const u16* __restrict__ Kc,
    u16* __restrict__ Pr, u16* __restrict__ Pc, float* __restrict__ Lp,
    const float* __restrict__ am, const float* __restrict__ cmask,
    float sReg, float sCul, int zoff) {
  __shared__ u16 lA[128 * 32];
  __shared__ u16 lB[128 * 32];
  const int tid = threadIdx.x, w = tid >> 6, lane = tid & 63;
  const int quad = lane >> 4, l15 = lane & 15;
  const int m0 = blockIdx.y * 128, n0 = blockIdx.x * 128;
  const int gz = zoff + blockIdx.z;
  const u16 *A, *BT;
  u16* P;
  const float* cm = nullptr;
  float scl;
  int K, b;
  if (gz < 12) {
    A = Qr + (size_t)gz * S_ * 128;
    BT = Kr + (size_t)gz * S_ * 128;
    K = 128;
    P = Pr + (size_t)blockIdx.z * (size_t)S_ * S_;
    scl = sReg;
    b = gz / 6;
  } else {
    int hc = gz - 12;
    A = Qc + (size_t)hc * S_ * 384;
    BT = Kc + (size_t)hc * S_ * 384;
    K = 384;
    P = Pc + (size_t)hc * (size_t)S_ * S_;
    b = hc >> 1;
    cm = cmask + (size_t)b * S_ * S_;
    scl = sCul;
  }

  const f32x4 z4 = {0.f, 0.f, 0.f, 0.f};
  f32x4 acc[4][4];
#pragma unroll
  for (int i = 0; i < 4; ++i)
#pragma unroll
    for (int j = 0; j < 4; ++j) acc[i][j] = z4;

  const int sr = w * 32 + (lane >> 2);
  const int scp = lane & 3;

  for (int kt = 0; kt < K; kt += 32) {
    int r1 = sr, r2 = sr + 16;
    int c1 = (scp - (r1 >> 2)) & 3;
    int c2 = (scp - (r2 >> 2)) & 3;
    gld16(A + (size_t)(m0 + r1) * K + kt + c1 * 8, &lA[r1 * 32 + scp * 8]);
    gld16(A + (size_t)(m0 + r2) * K + kt + c2 * 8, &lA[r2 * 32 + scp * 8]);
    gld16(BT + (size_t)(n0 + r1) * K + kt + c1 * 8, &lB[r1 * 32 + scp * 8]);
    gld16(BT + (size_t)(n0 + r2) * K + kt + c2 * 8, &lB[r2 * 32 + scp * 8]);
    __syncthreads();
    short8 af[4], bg[4];
#pragma unroll
    for (int i = 0; i < 4; ++i) {
      int r = (w >> 1) * 64 + i * 16 + l15;
      af[i] = *reinterpret_cast<const short8*>(&lA[r * 32 + ((quad + (r >> 2)) & 3) * 8]);
    }
#pragma unroll
    for (int j = 0; j < 4; ++j) {
      int r = (w & 1) * 64 + j * 16 + l15;
      bg[j] = *reinterpret_cast<const short8*>(&lB[r * 32 + ((quad + (r >> 2)) & 3) * 8]);
    }
#pragma unroll
    for (int i = 0; i < 4; ++i)
#pragma unroll
      for (int j = 0; j < 4; ++j)
        acc[i][j] = __builtin_amdgcn_mfma_f32_16x16x32_bf16(af[i], bg[j], acc[i][j], 0, 0, 0);
    __syncthreads();
  }

  // epilogue: p = exp2(acc*scl + am*l2e (+ cm*l2e) - M*l2e), write bf16 P,
  // accumulate per-row sums and reduce across the 16 col-lanes.
  const float* amb = am + b * S_;
  float pre[4];
#pragma unroll
  for (int j = 0; j < 4; ++j)
    pre[j] = fmaf(amb[n0 + (w & 1) * 64 + j * 16 + l15], L2E_, -FML2_);
  float lsum[4][4];
#pragma unroll
  for (int i = 0; i < 4; ++i)
#pragma unroll
    for (int r = 0; r < 4; ++r) lsum[i][r] = 0.f;

#pragma unroll
  for (int i = 0; i < 4; ++i) {
#pragma unroll
    for (int j = 0; j < 4; ++j) {
      int col = n0 + (w & 1) * 64 + j * 16 + l15;
#pragma unroll
      for (int r = 0; r < 4; ++r) {
        int row = m0 + (w >> 1) * 64 + i * 16 + quad * 4 + r;
        float v = fmaf(acc[i][j][r], scl, pre[j]);
        if (cm) v = fmaf(cm[(size_t)row * S_ + col], L2E_, v);
        float pv = exp2f(v);
        lsum[i][r] += pv;
        P[(size_t)row * S_ + col] = f2bf(pv);
      }
    }
  }
  const int nh64 = (n0 >> 6) + (w & 1);
#pragma unroll
  for (int i = 0; i < 4; ++i) {
#pragma unroll
    for (int r = 0; r < 4; ++r) {
      float s = lsum[i][r];
      s += __shfl_xor(s, 1);
      s += __shfl_xor(s, 2);
      s += __shfl_xor(s, 4);
      s += __shfl_xor(s, 8);
      if (l15 == 0) {
        int row = m0 + (w >> 1) * 64 + i * 16 + quad * 4 + r;
        Lp[(size_t)gz * (32 * S_) + nh64 * S_ + row] = s;
      }
    }
  }
}

// g2: O = P * V (K=S), normalize by l = sum of Lp halves, write bf16 into AO.
__global__ __launch_bounds__(256) void attn_g2_k(
    const u16* __restrict__ Pr, const u16* __restrict__ Pc,
    const u16* __restrict__ Vtr, const u16* __restrict__ Vtc,
    const float* __restrict__ Lp, u16* __restrict__ AO, int zoff) {
  const int gz = zoff + blockIdx.z;
  const int n0 = blockIdx.x * 128;
  const u16 *A, *BT;
  int b, colbase;
  if (gz < 12) {
    if (n0) return;  // N = 128: only x==0 active
    A = Pr + (size_t)blockIdx.z * (size_t)S_ * S_;
    BT = Vtr + (size_t)gz * 128 * S_;
    b = gz / 6;
    colbase = (gz % 6) * 128;
  } else {
    int hc = gz - 12;
    A = Pc + (size_t)hc * (size_t)S_ * S_;
    BT = Vtc + (size_t)hc * 384 * S_;
    b = hc >> 1;
    colbase = 768 + (hc & 1) * 384 + n0;
  }
  __shared__ u16 lA[128 * 32];
  __shared__ u16 lB[128 * 32];
  __shared__ float lL[128];
  const int tid = threadIdx.x, w = tid >> 6, lane = tid & 63;
  const int quad = lane >> 4, l15 = lane & 15;
  const int m0 = blockIdx.y * 128;

  if (tid < 128) {
    const float* lp = Lp + (size_t)gz * (32 * S_) + (m0 + tid);
    float s = 0.f;
#pragma unroll
    for (int g = 0; g < 32; ++g) s += lp[g * S_];
    lL[tid] = 1.f / s;
  }

  const f32x4 z4 = {0.f, 0.f, 0.f, 0.f};
  f32x4 acc[4][4];
#pragma unroll
  for (int i = 0; i < 4; ++i)
#pragma unroll
    for (int j = 0; j < 4; ++j) acc[i][j] = z4;

  const int sr = w * 32 + (lane >> 2);
  const int scp = lane & 3;

  for (int kt = 0; kt < S_; kt += 32) {
    int r1 = sr, r2 = sr + 16;
    int c1 = (scp - (r1 >> 2)) & 3;
    int c2 = (scp - (r2 >> 2)) & 3;
    gld16(A + (size_t)(m0 + r1) * S_ + kt + c1 * 8, &lA[r1 * 32 + scp * 8]);
    gld16(A + (size_t)(m0 + r2) * S_ + kt + c2 * 8, &lA[r2 * 32 + scp * 8]);
    gld16(BT + (size_t)(n0 + r1) * S_ + kt + c1 * 8, &lB[r1 * 32 + scp * 8]);
    gld16(BT + (size_t)(n0 + r2) * S_ + kt + c2 * 8, &lB[r2 * 32 + scp * 8]);
    __syncthreads();
    short8 af[4], bg[4];
#pragma unroll
    for (int i = 0; i < 4; ++i) {
      int r = (w >> 1) * 64 + i * 16 + l15;
      af[i] = *reinterpret_cast<const short8*>(&lA[r * 32 + ((quad + (r >> 2)) & 3) * 8]);
    }
#pragma unroll
    for (int j = 0; j < 4; ++j) {
      int r = (w & 1) * 64 + j * 16 + l15;
      bg[j] = *reinterpret_cast<const short8*>(&lB[r * 32 + ((quad + (r >> 2)) & 3) * 8]);
    }
#pragma unroll
    for (int i = 0; i < 4; ++i)
#pragma unroll
      for (int j = 0; j < 4; ++j)
        acc[i][j] = __builtin_amdgcn_mfma_f32_16x16x32_bf16(af[i], bg[j], acc[i][j], 0, 0, 0);
    __syncthreads();
  }

#pragma unroll
  for (int i = 0; i < 4; ++i) {
#pragma unroll
    for (int j = 0; j < 4; ++j) {
#pragma unroll
      for (int r = 0; r < 4; ++r) {
        int rl = (w >> 1) * 64 + i * 16 + quad * 4 + r;
        int row = m0 + rl;
        int col = colbase + (w & 1) * 64 + j * 16 + l15;
        AO[((size_t)(b * S_ + row)) * 1536 + col] = f2bf(acc[i][j][r] * lL[rl]);
      }
    }
  }
}

// ---------------- launcher ----------------

extern "C" void kernel_launch(void* const* d_in, const int* in_sizes, int n_in,
                              void* d_out, int out_size, void* d_ws, size_t ws_size,
                              hipStream_t stream) {
  const float* x     = (const float*)d_in[0];
  const float* cmask = (const float*)d_in[1];
  const float* amask = (const float*)d_in[2];
  const float* W[8]  = { (const float*)d_in[3], (const float*)d_in[4], (const float*)d_in[5],
                         (const float*)d_in[6], (const float*)d_in[7], (const float*)d_in[8],
                         (const float*)d_in[9], (const float*)d_in[10] };
  const float* rq_b = (const float*)d_in[11];
  const float* rk_b = (const float*)d_in[12];
  const float* rv_b = (const float*)d_in[13];
  const float* ro_b = (const float*)d_in[14];
  const float* cq_b = (const float*)d_in[15];
  const float* ck_b = (const float*)d_in[16];
  const float* cv_b = (const float*)d_in[17];
  const float* co_b = (const float*)d_in[18];
  const float* r_cb = (const float*)d_in[19];
  const float* c_cb = (const float*)d_in[20];
  const float* out_w = (const float*)d_in[21];
  const float* out_b = (const float*)d_in[22];

  char* p = (char*)d_ws;
  auto carve = [&](size_t bytes) -> void* {
    void* r = (void*)p;
    p += (bytes + 255) & ~(size_t)255;
    return r;
  };
  u16* Xb    = (u16*)carve((size_t)BS_ * E_ * 2);       // dead after QKV gemm
  u16* WqkvT = (u16*)carve((size_t)4608 * 768 * 2);     // dead after QKV gemm
  u16* roT   = (u16*)carve((size_t)768 * 768 * 2);
  u16* coT   = (u16*)carve((size_t)768 * 768 * 2);
  u16* outwT = (u16*)carve((size_t)768 * 1536 * 2);
  float* bqkv  = (float*)carve(4608 * 4);
  float* bproj = (float*)carve(1536 * 4);
  u16* Qr  = (u16*)carve((size_t)B_ * 6 * S_ * 128 * 2);
  u16* Kr  = (u16*)carve((size_t)B_ * 6 * S_ * 128 * 2);
  u16* Vtr = (u16*)carve((size_t)B_ * 6 * S_ * 128 * 2);
  u16* Qc  = (u16*)carve((size_t)B_ * 2 * S_ * 384 * 2);
  u16* Kc  = (u16*)carve((size_t)B_ * 2 * S_ * 384 * 2);
  u16* Vtc = (u16*)carve((size_t)B_ * 2 * S_ * 384 * 2);
  u16* AO  = (u16*)carve((size_t)BS_ * 1536 * 2);

  // Lp aliases dead Xb region (4.2 MB <= 6.3 MB).
  float* Lp = (float*)Xb;
  u16* Pcul = (u16*)carve((size_t)4 * S_ * S_ * 2);     // 33.6 MB
  size_t used = (size_t)(p - (char*)d_ws);
  size_t rem = (ws_size > used) ? (ws_size - used) : 0;
  int RCH;                                              // regular heads per chunk
  if      (rem >= (size_t)12 * S_ * S_ * 2 + 4096) RCH = 12;
  else if (rem >= (size_t)4  * S_ * S_ * 2 + 4096) RCH = 4;
  else                                             RCH = 2;
  u16* Preg = (u16*)carve((size_t)RCH * S_ * S_ * 2);
  u16* PR = Pcul;  // proj output: Pcul dead after attn_g2

  const float sReg = 0.08838834764831845f * L2E_;
  const float sCul = 0.05103103630798288f * L2E_;

  conv_x_k<<<dim3(BS_ * E_ / 4 / 256), 256, 0, stream>>>(x, Xb, BS_ * E_ / 4);
  bias_k<<<dim3(24), 256, 0, stream>>>(rq_b, rk_b, rv_b, cq_b, ck_b, cv_b,
                                       ro_b, co_b, r_cb, c_cb, bqkv, bproj);

  TP tp;
  const int wsel[6] = {0, 1, 2, 4, 5, 6};  // rq rk rv cq ck cv
  for (int i = 0; i < 6; ++i) {
    tp.src[i] = W[wsel[i]];
    tp.dst[i] = WqkvT + (size_t)i * 768 * 768;
    tp.rows[i] = 768;
  }
  tp.src[6] = W[3]; tp.dst[6] = roT;   tp.rows[6] = 768;   // ro_w
  tp.src[7] = W[7]; tp.dst[7] = coT;   tp.rows[7] = 768;   // co_w
  tp.src[8] = out_w; tp.dst[8] = outwT; tp.rows[8] = 1536; // out_w
  transpose_k<<<dim3(24, 48, 9), 256, 0, stream>>>(tp);

  // fused QKV projection for both branches (N = 6*768)
  gemm_k<2><<<dim3(36, 32), 256, 0, stream>>>(
      Xb, 768, WqkvT, 768, bqkv, 768,
      (const u16*)nullptr, 0, 0, (void*)nullptr, 0,
      Qr, Kr, Vtr, Qc, Kc, Vtc);

  if (RCH == 12) {
    // merged: all 16 heads in one g1 (4096 blocks) + one g2 (384 active blocks)
    attn_g1_k<<<dim3(16, 16, 16), 256, 0, stream>>>(
        Qr, Kr, Qc, Kc, Preg, Pcul, Lp, amask, cmask, sReg, sCul, 0);
    attn_g2_k<<<dim3(3, 16, 16), 256, 0, stream>>>(
        Preg, Pcul, Vtr, Vtc, Lp, AO, 0);
  } else {
    attn_g1_k<<<dim3(16, 16, 4), 256, 0, stream>>>(
        Qr, Kr, Qc, Kc, Preg, Pcul, Lp, amask, cmask, sReg, sCul, 12);
    attn_g2_k<<<dim3(3, 16, 4), 256, 0, stream>>>(
        Preg, Pcul, Vtr, Vtc, Lp, AO, 12);
    for (int c = 0; c < 12; c += RCH) {
      attn_g1_k<<<dim3(16, 16, RCH), 256, 0, stream>>>(
          Qr, Kr, Qc, Kc, Preg, Pcul, Lp, amask, cmask, sReg, sCul, c);
      attn_g2_k<<<dim3(1, 16, RCH), 256, 0, stream>>>(
          Preg, Pcul, Vtr, Vtc, Lp, AO, c);
    }
  }

  // merged per-branch output projections (block-diagonal select on n)
  gemm_k<0><<<dim3(12, 32), 256, 0, stream>>>(
      AO, 1536, roT, 768, bproj, 768,
      coT, 768, 768, (void*)PR, 1536,
      nullptr, nullptr, nullptr, nullptr, nullptr, nullptr);

  // final: PR[4096,1536] @ out_w + out_b -> fp32 d_out
  gemm_k<1><<<dim3(6, 32), 256, 0, stream>>>(
      PR, 1536, outwT, 1536, out_b, 1536,
      (const u16*)nullptr, 0, 0, d_out, 768,
      nullptr, nullptr, nullptr, nullptr, nullptr, nullptr);
}

// Round 5
// 403.098 us; speedup vs baseline: 1.5132x; 1.1441x over previous
//
#include <hip/hip_runtime.h>
#include <hip/hip_bf16.h>

using u16 = unsigned short;
using u32 = unsigned int;
typedef short short8 __attribute__((ext_vector_type(8)));
typedef float f32x4 __attribute__((ext_vector_type(4)));

#define B_  2
#define S_  2048
#define E_  768
#define BS_ 4096

#define L2E_ 1.44269504088896f
#define FML2_ 17.3123404906676f   // 12.0 * log2(e) fixed softmax stabilizer

__device__ __forceinline__ u16 f2bf(float f) {
  __hip_bfloat16 h = __float2bfloat16(f);
  return *reinterpret_cast<u16*>(&h);
}

__device__ __forceinline__ u32 pk2(float a, float b) {
  return (u32)f2bf(a) | ((u32)f2bf(b) << 16);
}

// async global->LDS, 16B per lane. LDS dest must be wave-uniform base + lane*16.
__device__ __forceinline__ void gld16(const void* g, void* l) {
  __builtin_amdgcn_global_load_lds(
      (const __attribute__((address_space(1))) u32*)g,
      (__attribute__((address_space(3))) u32*)l, 16, 0, 0);
}

// ---------------- conversion / misc kernels ----------------

__global__ __launch_bounds__(256) void conv_x_k(const float* __restrict__ x,
                                                u16* __restrict__ xb, int n4) {
  int i = blockIdx.x * 256 + threadIdx.x;
  if (i >= n4) return;
  float4 v = reinterpret_cast<const float4*>(x)[i];
  reinterpret_cast<uint2*>(xb)[i] = make_uint2(pk2(v.x, v.y), pk2(v.z, v.w));
}

__global__ __launch_bounds__(256) void bias_k(
    const float* rqb, const float* rkb, const float* rvb,
    const float* cqb, const float* ckb, const float* cvb,
    const float* rob, const float* cob,
    const float* rcb, const float* ccb,
    float* bqkv, float* bproj) {
  int t = blockIdx.x * 256 + threadIdx.x;
  if (t < 4608) {
    int seg = t / 768, i = t - seg * 768;
    float v = 0.f;
    if      (seg == 0) v = rqb[i] + rcb[i];   // cultural bias folds into Q bias
    else if (seg == 1) v = rkb[i];
    else if (seg == 2) v = rvb[i];
    else if (seg == 3) v = cqb[i] + ccb[i];
    else if (seg == 4) v = ckb[i];
    else               v = cvb[i];
    bqkv[t] = v;
  } else {
    int u = t - 4608;
    if (u < 1536) bproj[u] = (u < 768) ? rob[u] : cob[u - 768];
  }
}

struct TP {
  const float* src[9];
  u16* dst[9];
  int rows[9];
};

// dst[c][r] = bf16(src[r][c]); src is [rows][768]
__global__ __launch_bounds__(256) void transpose_k(TP p) {
  int mi = blockIdx.z;
  int rows = p.rows[mi];
  int r0 = blockIdx.y * 32;
  if (r0 >= rows) return;
  int c0 = blockIdx.x * 32;
  const float* src = p.src[mi];
  u16* dst = p.dst[mi];
  __shared__ float t[32][33];
  int tx = threadIdx.x & 31, ty = threadIdx.x >> 5;
#pragma unroll
  for (int d = 0; d < 4; ++d) {
    int r = ty + d * 8;
    t[r][tx] = src[(size_t)(r0 + r) * 768 + c0 + tx];
  }
  __syncthreads();
#pragma unroll
  for (int d = 0; d < 4; ++d) {
    int c = ty + d * 8;
    dst[(size_t)(c0 + c) * rows + r0 + tx] = f2bf(t[tx][c]);
  }
}

// ============ transposed GEMM: computes C^T, i.e. C[row=M][col=N] with
// A[M][K], BT[N][K]; lane's 4 acc values are CONSECUTIVE M-rows -> packed
// 8B stores. MODE 0: PROJ (bf16 -> Cout[col*ldc+row], m-split A select)
// MODE 1: FINAL (fp32 float4 -> Cout[col*ldc+row])
// MODE 2: QKVT routing (M=feature, N=token) ============

template<int MODE>
__global__ __launch_bounds__(256) void gemm_t_k(
    const u16* __restrict__ A, int lda,
    const u16* __restrict__ BT, int ldb,
    const float* __restrict__ bias, int K,
    const u16* __restrict__ A2, int msplit, int bofs,
    void* __restrict__ Cout, int ldc,
    u16* __restrict__ Qr, u16* __restrict__ Kr, u16* __restrict__ Vtr,
    u16* __restrict__ Qc, u16* __restrict__ Kc, u16* __restrict__ Vtc) {
  __shared__ u16 lA[128 * 32];
  __shared__ u16 lB[128 * 32];
  const int tid = threadIdx.x, w = tid >> 6, lane = tid & 63;
  const int quad = lane >> 4, l15 = lane & 15;
  const int m0 = blockIdx.y * 128, n0 = blockIdx.x * 128;
  if (msplit && m0 >= msplit) { A = A2 - (size_t)msplit * lda; BT += bofs; }

  const f32x4 z4 = {0.f, 0.f, 0.f, 0.f};
  f32x4 acc[4][4];
#pragma unroll
  for (int i = 0; i < 4; ++i)
#pragma unroll
    for (int j = 0; j < 4; ++j) acc[i][j] = z4;

  const int sr = w * 32 + (lane >> 2);
  const int scp = lane & 3;

  for (int kt = 0; kt < K; kt += 32) {
    int r1 = sr, r2 = sr + 16;
    int c1 = (scp - (r1 >> 2)) & 3;
    int c2 = (scp - (r2 >> 2)) & 3;
    gld16(A + (size_t)(m0 + r1) * lda + kt + c1 * 8, &lA[r1 * 32 + scp * 8]);
    gld16(A + (size_t)(m0 + r2) * lda + kt + c2 * 8, &lA[r2 * 32 + scp * 8]);
    gld16(BT + (size_t)(n0 + r1) * ldb + kt + c1 * 8, &lB[r1 * 32 + scp * 8]);
    gld16(BT + (size_t)(n0 + r2) * ldb + kt + c2 * 8, &lB[r2 * 32 + scp * 8]);
    __syncthreads();
    short8 af[4], bg[4];
#pragma unroll
    for (int i = 0; i < 4; ++i) {
      int r = (w >> 1) * 64 + i * 16 + l15;
      af[i] = *reinterpret_cast<const short8*>(&lA[r * 32 + ((quad + (r >> 2)) & 3) * 8]);
    }
#pragma unroll
    for (int j = 0; j < 4; ++j) {
      int r = (w & 1) * 64 + j * 16 + l15;
      bg[j] = *reinterpret_cast<const short8*>(&lB[r * 32 + ((quad + (r >> 2)) & 3) * 8]);
    }
#pragma unroll
    for (int i = 0; i < 4; ++i)
#pragma unroll
      for (int j = 0; j < 4; ++j)
        acc[i][j] = __builtin_amdgcn_mfma_f32_16x16x32_bf16(af[i], bg[j], acc[i][j], 0, 0, 0);
    __syncthreads();
  }

  const int seg = (MODE == 2) ? (m0 / 768) : 0;
#pragma unroll
  for (int i = 0; i < 4; ++i) {
    int f = m0 + (w >> 1) * 64 + i * 16 + quad * 4;   // M-row base (4 consecutive)
    float4 b4 = *reinterpret_cast<const float4*>(bias + f);
#pragma unroll
    for (int j = 0; j < 4; ++j) {
      int t = n0 + (w & 1) * 64 + j * 16 + l15;        // N-col
      float v0 = acc[i][j][0] + b4.x;
      float v1 = acc[i][j][1] + b4.y;
      float v2 = acc[i][j][2] + b4.z;
      float v3 = acc[i][j][3] + b4.w;
      if (MODE == 0) {
        *reinterpret_cast<uint2*>((u16*)Cout + (size_t)t * ldc + f) =
            make_uint2(pk2(v0, v1), pk2(v2, v3));
      } else if (MODE == 1) {
        *reinterpret_cast<float4*>((float*)Cout + (size_t)t * ldc + f) =
            make_float4(v0, v1, v2, v3);
      } else {
        int b = t >> 11, s = t & 2047;
        int fs = f - seg * 768;
        if (seg == 0) {
          int h = fs >> 7, d = fs & 127;
          *reinterpret_cast<uint2*>(Qr + ((size_t)(b * 6 + h) * 2048 + s) * 128 + d) =
              make_uint2(pk2(v0, v1), pk2(v2, v3));
        } else if (seg == 1) {
          int h = fs >> 7, d = fs & 127;
          *reinterpret_cast<uint2*>(Kr + ((size_t)(b * 6 + h) * 2048 + s) * 128 + d) =
              make_uint2(pk2(v0, v1), pk2(v2, v3));
        } else if (seg == 2) {
          int h = fs >> 7, d = fs & 127;
          u16* vp = Vtr + ((size_t)(b * 6 + h) * 128 + d) * 2048 + s;
          vp[0] = f2bf(v0); vp[2048] = f2bf(v1); vp[4096] = f2bf(v2); vp[6144] = f2bf(v3);
        } else if (seg == 3) {
          int h = fs / 384, d = fs - h * 384;
          *reinterpret_cast<uint2*>(Qc + ((size_t)(b * 2 + h) * 2048 + s) * 384 + d) =
              make_uint2(pk2(v0, v1), pk2(v2, v3));
        } else if (seg == 4) {
          int h = fs / 384, d = fs - h * 384;
          *reinterpret_cast<uint2*>(Kc + ((size_t)(b * 2 + h) * 2048 + s) * 384 + d) =
              make_uint2(pk2(v0, v1), pk2(v2, v3));
        } else {
          int h = fs / 384, d = fs - h * 384;
          u16* vp = Vtc + ((size_t)(b * 2 + h) * 384 + d) * 2048 + s;
          vp[0] = f2bf(v0); vp[2048] = f2bf(v1); vp[4096] = f2bf(v2); vp[6144] = f2bf(v3);
        }
      }
    }
  }
}

// ---------------- attention g1 (transposed): S^T[k][q] = K·Q^T ----------------
// A = K-matrix (M=keys), BT = Q-matrix (N=queries); lane's 4 values are
// consecutive KEYS -> P[q][k] written as packed uint2; cm/am as float4 loads.
// Row-sums over keys: 2 shfl_xor + 32-partial Lp[gz][32][S].
__global__ __launch_bounds__(256) void attn_g1_k(
    const u16* __restrict__ Qr, const u16* __restrict__ Kr,
    const u16* __restrict__ Qc, const u16* __restrict__ Kc,
    u16* __restrict__ Pr, u16* __restrict__ Pc, float* __restrict__ Lp,
    const float* __restrict__ am, const float* __restrict__ cmask,
    float sReg, float sCul, int zoff) {
  __shared__ u16 lA[128 * 32];
  __shared__ u16 lB[128 * 32];
  const int tid = threadIdx.x, w = tid >> 6, lane = tid & 63;
  const int quad = lane >> 4, l15 = lane & 15;
  const int m0 = blockIdx.y * 128, n0 = blockIdx.x * 128;  // m=key, n=query
  const int gz = zoff + blockIdx.z;
  const u16 *A, *BT;
  u16* P;
  const float* cm = nullptr;
  float scl;
  int K, b;
  if (gz < 12) {
    A = Kr + (size_t)gz * S_ * 128;
    BT = Qr + (size_t)gz * S_ * 128;
    K = 128;
    P = Pr + (size_t)blockIdx.z * (size_t)S_ * S_;
    scl = sReg;
    b = gz / 6;
  } else {
    int hc = gz - 12;
    A = Kc + (size_t)hc * S_ * 384;
    BT = Qc + (size_t)hc * S_ * 384;
    K = 384;
    P = Pc + (size_t)hc * (size_t)S_ * S_;
    b = hc >> 1;
    cm = cmask + (size_t)b * S_ * S_;
    scl = sCul;
  }

  const f32x4 z4 = {0.f, 0.f, 0.f, 0.f};
  f32x4 acc[4][4];
#pragma unroll
  for (int i = 0; i < 4; ++i)
#pragma unroll
    for (int j = 0; j < 4; ++j) acc[i][j] = z4;

  const int sr = w * 32 + (lane >> 2);
  const int scp = lane & 3;

  for (int kt = 0; kt < K; kt += 32) {
    int r1 = sr, r2 = sr + 16;
    int c1 = (scp - (r1 >> 2)) & 3;
    int c2 = (scp - (r2 >> 2)) & 3;
    gld16(A + (size_t)(m0 + r1) * K + kt + c1 * 8, &lA[r1 * 32 + scp * 8]);
    gld16(A + (size_t)(m0 + r2) * K + kt + c2 * 8, &lA[r2 * 32 + scp * 8]);
    gld16(BT + (size_t)(n0 + r1) * K + kt + c1 * 8, &lB[r1 * 32 + scp * 8]);
    gld16(BT + (size_t)(n0 + r2) * K + kt + c2 * 8, &lB[r2 * 32 + scp * 8]);
    __syncthreads();
    short8 af[4], bg[4];
#pragma unroll
    for (int i = 0; i < 4; ++i) {
      int r = (w >> 1) * 64 + i * 16 + l15;
      af[i] = *reinterpret_cast<const short8*>(&lA[r * 32 + ((quad + (r >> 2)) & 3) * 8]);
    }
#pragma unroll
    for (int j = 0; j < 4; ++j) {
      int r = (w & 1) * 64 + j * 16 + l15;
      bg[j] = *reinterpret_cast<const short8*>(&lB[r * 32 + ((quad + (r >> 2)) & 3) * 8]);
    }
#pragma unroll
    for (int i = 0; i < 4; ++i)
#pragma unroll
      for (int j = 0; j < 4; ++j)
        acc[i][j] = __builtin_amdgcn_mfma_f32_16x16x32_bf16(af[i], bg[j], acc[i][j], 0, 0, 0);
    __syncthreads();
  }

  // epilogue: p = exp2(acc*scl + am[k]*l2e (+ cm[q][k]*l2e) - M), packed stores
  const float* amb = am + b * S_;
  float lsum[4] = {0.f, 0.f, 0.f, 0.f};
#pragma unroll
  for (int i = 0; i < 4; ++i) {
    int kb = m0 + (w >> 1) * 64 + i * 16 + quad * 4;    // 4 consecutive keys
    float4 a4 = *reinterpret_cast<const float4*>(amb + kb);
    float pre0 = fmaf(a4.x, L2E_, -FML2_);
    float pre1 = fmaf(a4.y, L2E_, -FML2_);
    float pre2 = fmaf(a4.z, L2E_, -FML2_);
    float pre3 = fmaf(a4.w, L2E_, -FML2_);
#pragma unroll
    for (int j = 0; j < 4; ++j) {
      int q = n0 + (w & 1) * 64 + j * 16 + l15;
      float c0 = pre0, c1 = pre1, c2 = pre2, c3 = pre3;
      if (cm) {
        float4 cmv = *reinterpret_cast<const float4*>(cm + (size_t)q * S_ + kb);
        c0 = fmaf(cmv.x, L2E_, c0);
        c1 = fmaf(cmv.y, L2E_, c1);
        c2 = fmaf(cmv.z, L2E_, c2);
        c3 = fmaf(cmv.w, L2E_, c3);
      }
      float p0 = exp2f(fmaf(acc[i][j][0], scl, c0));
      float p1 = exp2f(fmaf(acc[i][j][1], scl, c1));
      float p2 = exp2f(fmaf(acc[i][j][2], scl, c2));
      float p3 = exp2f(fmaf(acc[i][j][3], scl, c3));
      lsum[j] += (p0 + p1) + (p2 + p3);
      *reinterpret_cast<uint2*>(P + (size_t)q * S_ + kb) =
          make_uint2(pk2(p0, p1), pk2(p2, p3));
    }
  }
#pragma unroll
  for (int j = 0; j < 4; ++j) {
    float s = lsum[j];
    s += __shfl_xor(s, 16);
    s += __shfl_xor(s, 32);
    if (lane < 16)
      Lp[(size_t)gz * (32 * S_) + ((size_t)((m0 >> 7) * 2 + (w >> 1))) * S_ +
         n0 + (w & 1) * 64 + j * 16 + lane] = s;
  }
}

// ---------------- attention g2 (transposed): O^T[d][q] = Vt·P^T ----------------
// A = Vt (M=HD), BT = P[q][k] natural (N=queries), K = S_. Normalize by 1/l[q],
// write packed uint2 into AO[token][feature] (4 consecutive features).
__global__ __launch_bounds__(256) void attn_g2_k(
    const u16* __restrict__ Pr, const u16* __restrict__ Pc,
    const u16* __restrict__ Vtr, const u16* __restrict__ Vtc,
    const float* __restrict__ Lp, u16* __restrict__ AO, int zoff) {
  const int gz = zoff + blockIdx.z;
  const int m0 = blockIdx.y * 128, n0 = blockIdx.x * 128;  // m=feat, n=query
  const u16 *A, *BT;
  int b, colbase;
  if (gz < 12) {
    if (blockIdx.y) return;  // M = 128
    A = Vtr + (size_t)gz * 128 * S_;
    BT = Pr + (size_t)blockIdx.z * (size_t)S_ * S_;
    b = gz / 6;
    colbase = (gz % 6) * 128;
  } else {
    int hc = gz - 12;
    A = Vtc + (size_t)hc * 384 * S_;
    BT = Pc + (size_t)hc * (size_t)S_ * S_;
    b = hc >> 1;
    colbase = 768 + (hc & 1) * 384;
  }
  __shared__ u16 lA[128 * 32];
  __shared__ u16 lB[128 * 32];
  __shared__ float lL[128];
  const int tid = threadIdx.x, w = tid >> 6, lane = tid & 63;
  const int quad = lane >> 4, l15 = lane & 15;

  if (tid < 128) {
    const float* lp = Lp + (size_t)gz * (32 * S_) + (n0 + tid);
    float s = 0.f;
#pragma unroll
    for (int g = 0; g < 32; ++g) s += lp[(size_t)g * S_];
    lL[tid] = 1.f / s;
  }

  const f32x4 z4 = {0.f, 0.f, 0.f, 0.f};
  f32x4 acc[4][4];
#pragma unroll
  for (int i = 0; i < 4; ++i)
#pragma unroll
    for (int j = 0; j < 4; ++j) acc[i][j] = z4;

  const int sr = w * 32 + (lane >> 2);
  const int scp = lane & 3;

  for (int kt = 0; kt < S_; kt += 32) {
    int r1 = sr, r2 = sr + 16;
    int c1 = (scp - (r1 >> 2)) & 3;
    int c2 = (scp - (r2 >> 2)) & 3;
    gld16(A + (size_t)(m0 + r1) * S_ + kt + c1 * 8, &lA[r1 * 32 + scp * 8]);
    gld16(A + (size_t)(m0 + r2) * S_ + kt + c2 * 8, &lA[r2 * 32 + scp * 8]);
    gld16(BT + (size_t)(n0 + r1) * S_ + kt + c1 * 8, &lB[r1 * 32 + scp * 8]);
    gld16(BT + (size_t)(n0 + r2) * S_ + kt + c2 * 8, &lB[r2 * 32 + scp * 8]);
    __syncthreads();
    short8 af[4], bg[4];
#pragma unroll
    for (int i = 0; i < 4; ++i) {
      int r = (w >> 1) * 64 + i * 16 + l15;
      af[i] = *reinterpret_cast<const short8*>(&lA[r * 32 + ((quad + (r >> 2)) & 3) * 8]);
    }
#pragma unroll
    for (int j = 0; j < 4; ++j) {
      int r = (w & 1) * 64 + j * 16 + l15;
      bg[j] = *reinterpret_cast<const short8*>(&lB[r * 32 + ((quad + (r >> 2)) & 3) * 8]);
    }
#pragma unroll
    for (int i = 0; i < 4; ++i)
#pragma unroll
      for (int j = 0; j < 4; ++j)
        acc[i][j] = __builtin_amdgcn_mfma_f32_16x16x32_bf16(af[i], bg[j], acc[i][j], 0, 0, 0);
    __syncthreads();
  }

  float invl[4];
#pragma unroll
  for (int j = 0; j < 4; ++j) invl[j] = lL[(w & 1) * 64 + j * 16 + l15];
#pragma unroll
  for (int i = 0; i < 4; ++i) {
    int feat = colbase + m0 + (w >> 1) * 64 + i * 16 + quad * 4;
#pragma unroll
    for (int j = 0; j < 4; ++j) {
      int q = n0 + (w & 1) * 64 + j * 16 + l15;
      float v0 = acc[i][j][0] * invl[j];
      float v1 = acc[i][j][1] * invl[j];
      float v2 = acc[i][j][2] * invl[j];
      float v3 = acc[i][j][3] * invl[j];
      *reinterpret_cast<uint2*>(AO + ((size_t)(b * S_ + q)) * 1536 + feat) =
          make_uint2(pk2(v0, v1), pk2(v2, v3));
    }
  }
}

// ---------------- launcher ----------------

extern "C" void kernel_launch(void* const* d_in, const int* in_sizes, int n_in,
                              void* d_out, int out_size, void* d_ws, size_t ws_size,
                              hipStream_t stream) {
  const float* x     = (const float*)d_in[0];
  const float* cmask = (const float*)d_in[1];
  const float* amask = (const float*)d_in[2];
  const float* W[8]  = { (const float*)d_in[3], (const float*)d_in[4], (const float*)d_in[5],
                         (const float*)d_in[6], (const float*)d_in[7], (const float*)d_in[8],
                         (const float*)d_in[9], (const float*)d_in[10] };
  const float* rq_b = (const float*)d_in[11];
  const float* rk_b = (const float*)d_in[12];
  const float* rv_b = (const float*)d_in[13];
  const float* ro_b = (const float*)d_in[14];
  const float* cq_b = (const float*)d_in[15];
  const float* ck_b = (const float*)d_in[16];
  const float* cv_b = (const float*)d_in[17];
  const float* co_b = (const float*)d_in[18];
  const float* r_cb = (const float*)d_in[19];
  const float* c_cb = (const float*)d_in[20];
  const float* out_w = (const float*)d_in[21];
  const float* out_b = (const float*)d_in[22];

  char* p = (char*)d_ws;
  auto carve = [&](size_t bytes) -> void* {
    void* r = (void*)p;
    p += (bytes + 255) & ~(size_t)255;
    return r;
  };
  u16* Xb    = (u16*)carve((size_t)BS_ * E_ * 2);       // dead after QKV gemm
  u16* WqkvT = (u16*)carve((size_t)4608 * 768 * 2);     // dead after QKV gemm
  u16* roT   = (u16*)carve((size_t)768 * 768 * 2);
  u16* coT   = (u16*)carve((size_t)768 * 768 * 2);
  u16* outwT = (u16*)carve((size_t)768 * 1536 * 2);
  float* bqkv  = (float*)carve(4608 * 4);
  float* bproj = (float*)carve(1536 * 4);
  u16* Qr  = (u16*)carve((size_t)B_ * 6 * S_ * 128 * 2);
  u16* Kr  = (u16*)carve((size_t)B_ * 6 * S_ * 128 * 2);
  u16* Vtr = (u16*)carve((size_t)B_ * 6 * S_ * 128 * 2);
  u16* Qc  = (u16*)carve((size_t)B_ * 2 * S_ * 384 * 2);
  u16* Kc  = (u16*)carve((size_t)B_ * 2 * S_ * 384 * 2);
  u16* Vtc = (u16*)carve((size_t)B_ * 2 * S_ * 384 * 2);
  u16* AO  = (u16*)carve((size_t)BS_ * 1536 * 2);

  // Lp aliases dead Xb region (4.2 MB <= 6.3 MB).
  float* Lp = (float*)Xb;
  u16* Pcul = (u16*)carve((size_t)4 * S_ * S_ * 2);     // 33.6 MB
  size_t used = (size_t)(p - (char*)d_ws);
  size_t rem = (ws_size > used) ? (ws_size - used) : 0;
  int RCH;                                              // regular heads per chunk
  if      (rem >= (size_t)12 * S_ * S_ * 2 + 4096) RCH = 12;
  else if (rem >= (size_t)4  * S_ * S_ * 2 + 4096) RCH = 4;
  else                                             RCH = 2;
  u16* Preg = (u16*)carve((size_t)RCH * S_ * S_ * 2);
  u16* PR = Pcul;  // proj output: Pcul dead after attn_g2

  const float sReg = 0.08838834764831845f * L2E_;
  const float sCul = 0.05103103630798288f * L2E_;

  conv_x_k<<<dim3(BS_ * E_ / 4 / 256), 256, 0, stream>>>(x, Xb, BS_ * E_ / 4);
  bias_k<<<dim3(24), 256, 0, stream>>>(rq_b, rk_b, rv_b, cq_b, ck_b, cv_b,
                                       ro_b, co_b, r_cb, c_cb, bqkv, bproj);

  TP tp;
  const int wsel[6] = {0, 1, 2, 4, 5, 6};  // rq rk rv cq ck cv
  for (int i = 0; i < 6; ++i) {
    tp.src[i] = W[wsel[i]];
    tp.dst[i] = WqkvT + (size_t)i * 768 * 768;
    tp.rows[i] = 768;
  }
  tp.src[6] = W[3]; tp.dst[6] = roT;   tp.rows[6] = 768;   // ro_w
  tp.src[7] = W[7]; tp.dst[7] = coT;   tp.rows[7] = 768;   // co_w
  tp.src[8] = out_w; tp.dst[8] = outwT; tp.rows[8] = 1536; // out_w
  transpose_k<<<dim3(24, 48, 9), 256, 0, stream>>>(tp);

  // fused QKV projection, transposed: M=4608 features, N=4096 tokens
  gemm_t_k<2><<<dim3(32, 36), 256, 0, stream>>>(
      WqkvT, 768, Xb, 768, bqkv, 768,
      (const u16*)nullptr, 0, 0, (void*)nullptr, 0,
      Qr, Kr, Vtr, Qc, Kc, Vtc);

  if (RCH == 12) {
    attn_g1_k<<<dim3(16, 16, 16), 256, 0, stream>>>(
        Qr, Kr, Qc, Kc, Preg, Pcul, Lp, amask, cmask, sReg, sCul, 0);
    attn_g2_k<<<dim3(16, 3, 16), 256, 0, stream>>>(
        Preg, Pcul, Vtr, Vtc, Lp, AO, 0);
  } else {
    attn_g1_k<<<dim3(16, 16, 4), 256, 0, stream>>>(
        Qr, Kr, Qc, Kc, Preg, Pcul, Lp, amask, cmask, sReg, sCul, 12);
    attn_g2_k<<<dim3(16, 3, 4), 256, 0, stream>>>(
        Preg, Pcul, Vtr, Vtc, Lp, AO, 12);
    for (int c = 0; c < 12; c += RCH) {
      attn_g1_k<<<dim3(16, 16, RCH), 256, 0, stream>>>(
          Qr, Kr, Qc, Kc, Preg, Pcul, Lp, amask, cmask, sReg, sCul, c);
      attn_g2_k<<<dim3(16, 1, RCH), 256, 0, stream>>>(
          Preg, Pcul, Vtr, Vtc, Lp, AO, c);
    }
  }

  // merged per-branch output projections, transposed (m-split selects coT)
  gemm_t_k<0><<<dim3(32, 12), 256, 0, stream>>>(
      roT, 768, AO, 1536, bproj, 768,
      coT, 768, 768, (void*)PR, 1536,
      nullptr, nullptr, nullptr, nullptr, nullptr, nullptr);

  // final, transposed: M=768 out-features, N=4096 tokens -> fp32 float4 stores
  gemm_t_k<1><<<dim3(32, 6), 256, 0, stream>>>(
      outwT, 1536, PR, 1536, out_b, 1536,
      (const u16*)nullptr, 0, 0, d_out, 768,
      nullptr, nullptr, nullptr, nullptr, nullptr, nullptr);
}